// Round 9
// baseline (301.680 us; speedup 1.0000x reference)
//
#include <hip/hip_runtime.h>
#include <math.h>

// Problem constants
constexpr int kB   = 4;
constexpr int kL   = 1024;
constexpr int kDM  = 768;
constexpr int kDI  = 1536;   // 2*kDM
constexpr int kDS  = 16;     // D_STATE
constexpr int kDTR = 48;     // DT_RANK
constexpr int kNX  = 80;     // DTR + 2*DS
constexpr int kM   = kB * kL; // 4096
constexpr int kLTXT = 128;

typedef __attribute__((ext_vector_type(8))) short bf16x8;
typedef __attribute__((ext_vector_type(4))) float f32x4;

__device__ inline unsigned short f2bf(float f) {
    unsigned u = __float_as_uint(f);
    u = (u + 0x7FFFu + ((u >> 16) & 1u)) >> 16;   // RNE
    return (unsigned short)u;
}

__device__ __forceinline__ void gl2lds16(const unsigned short* g, unsigned short* l) {
    __builtin_amdgcn_global_load_lds(
        (const __attribute__((address_space(1))) unsigned int*)g,
        (__attribute__((address_space(3))) unsigned int*)l, 16, 0, 0);
}

// ---------------------------------------------------------------------------
// txt[b][j] = b_txt[j] + sum_k text_tokens[b,0,k] * W_txt[j,k]
__global__ __launch_bounds__(256) void txt_kernel(
    const float* __restrict__ text, const float* __restrict__ Wt,
    const float* __restrict__ bt, float* __restrict__ txt)
{
    int gw = blockIdx.x * 4 + (threadIdx.x >> 6);
    int lane = threadIdx.x & 63;
    int b = gw / kDM;
    int j = gw - b * kDM;
    const float* trow = text + (size_t)b * kLTXT * kDM;
    const float* wrow = Wt + (size_t)j * kDM;
    float acc = 0.f;
    for (int k = lane; k < kDM; k += 64) acc = fmaf(trow[k], wrow[k], acc);
    #pragma unroll
    for (int o = 32; o; o >>= 1) acc += __shfl_xor(acc, o, 64);
    if (lane == 0) txt[gw] = acc + bt[j];
}

// ---------------------------------------------------------------------------
// tokens_bf16[m][k] = bf16(image[m][k] + txt[m/1024][k])
__global__ __launch_bounds__(256) void tokens_bf16_kernel(
    const float* __restrict__ img, const float* __restrict__ txt,
    unsigned short* __restrict__ tok)
{
    int i = blockIdx.x * 256 + threadIdx.x;        // over kM*kDM/4
    float4 a = ((const float4*)img)[i];
    int m = i / (kDM / 4);
    int k4 = i - m * (kDM / 4);
    float4 tv = ((const float4*)(txt + (size_t)(m >> 10) * kDM))[k4];
    ushort4 o;
    o.x = f2bf(a.x + tv.x); o.y = f2bf(a.y + tv.y);
    o.z = f2bf(a.z + tv.z); o.w = f2bf(a.w + tv.w);
    ((ushort4*)tok)[i] = o;
}

// ---------------------------------------------------------------------------
// cast in_proj_w (f32, [3072][768]) -> bf16
__global__ __launch_bounds__(256) void castw_kernel(
    const float* __restrict__ w, unsigned short* __restrict__ o, int n4)
{
    int i = blockIdx.x * 256 + threadIdx.x;
    if (i >= n4) return;
    float4 a = ((const float4*)w)[i];
    ushort4 v;
    v.x = f2bf(a.x); v.y = f2bf(a.y); v.z = f2bf(a.z); v.w = f2bf(a.w);
    ((ushort4*)o)[i] = v;
}

// ---------------------------------------------------------------------------
// bf16 MFMA GEMM for in_proj (global_load_lds width-16, double-buffered LDS).
// M=4096, N=3072, K=768. BM=BN=128, BK=32, 256 threads (4 waves, 2x2).
// n<1536 -> xout; n>=1536 -> gout = silu(v)
__global__ __launch_bounds__(256) void mfma_inproj_kernel(
    const unsigned short* __restrict__ A, const unsigned short* __restrict__ W,
    float* __restrict__ xout, float* __restrict__ gout)
{
    __shared__ unsigned short Asm[2][128][32];
    __shared__ unsigned short Wsm[2][128][32];
    const int t = threadIdx.x;
    const int lane = t & 63;
    const int wv = t >> 6;             // wave 0..3
    const int wr = wv >> 1, wc = wv & 1;
    const int m0 = blockIdx.x * 128;
    const int n0 = blockIdx.y * 128;

    const int srow = lane >> 2;          // 0..15
    const int scol = (lane & 3) * 8;     // bf16 elem 0,8,16,24
    const unsigned short* agp  = A + (size_t)(m0 + wv * 32 + srow) * kDM + scol;
    const unsigned short* agp2 = agp + 16 * kDM;
    const unsigned short* wgp  = W + (size_t)(n0 + wv * 32 + srow) * kDM + scol;
    const unsigned short* wgp2 = wgp + 16 * kDM;

    auto stage = [&](int buf, int k0) {
        gl2lds16(agp  + k0, &Asm[buf][wv * 32][0]);
        gl2lds16(agp2 + k0, &Asm[buf][wv * 32 + 16][0]);
        gl2lds16(wgp  + k0, &Wsm[buf][wv * 32][0]);
        gl2lds16(wgp2 + k0, &Wsm[buf][wv * 32 + 16][0]);
    };

    f32x4 acc[4][4] = {};
    const int fr = lane & 15;
    const int fk = (lane >> 4) * 8;

    stage(0, 0);
    __syncthreads();

    int buf = 0;
    for (int k0 = 0; k0 < kDM; k0 += 32) {
        if (k0 + 32 < kDM) stage(buf ^ 1, k0 + 32);
        bf16x8 af[4], wf[4];
        #pragma unroll
        for (int i = 0; i < 4; ++i)
            af[i] = *(const bf16x8*)&Asm[buf][wr * 64 + i * 16 + fr][fk];
        #pragma unroll
        for (int j = 0; j < 4; ++j)
            wf[j] = *(const bf16x8*)&Wsm[buf][wc * 64 + j * 16 + fr][fk];
        #pragma unroll
        for (int i = 0; i < 4; ++i)
            #pragma unroll
            for (int j = 0; j < 4; ++j)
                acc[i][j] = __builtin_amdgcn_mfma_f32_16x16x32_bf16(af[i], wf[j], acc[i][j], 0, 0, 0);
        __syncthreads();
        buf ^= 1;
    }

    const int erow = (lane >> 4) * 4;
    const int ecol = lane & 15;
    #pragma unroll
    for (int i = 0; i < 4; ++i) {
        #pragma unroll
        for (int j = 0; j < 4; ++j) {
            const int gn = n0 + wc * 64 + j * 16 + ecol;
            #pragma unroll
            for (int q = 0; q < 4; ++q) {
                const int gm = m0 + wr * 64 + i * 16 + erow + q;
                float v = acc[i][j][q];
                if (gn < kDI) {
                    xout[(size_t)gm * kDI + gn] = v;
                } else {
                    gout[(size_t)gm * kDI + (gn - kDI)] = v / (1.f + __expf(-v));
                }
            }
        }
    }
}

// ---------------------------------------------------------------------------
// x_proj split-K: part[ks][m][n] = sum_{k in seg ks} x[m][k] * W[n][k]
constexpr int kKS   = 8;
constexpr int kKSEG = kDI / kKS;   // 192

__global__ __launch_bounds__(256) void xproj_splitk_kernel(
    const float* __restrict__ A, const float* __restrict__ W,
    float* __restrict__ part)
{
    __shared__ float As[16][68];
    __shared__ float Ws[16][84];
    const int t = threadIdx.x;
    const int m0 = blockIdx.x * 64;
    const int kbase = blockIdx.y * kKSEG;
    const int lrow = t >> 2, lk4 = (t & 3) << 2;
    const int ci = (t & 15) << 2;      // 4 rows
    const int cj = (t >> 4) * 5;       // 5 cols (16*5 = 80)
    float acc[4][5] = {};
    const float* aptr = A + (size_t)(m0 + lrow) * kDI + kbase + lk4;

    for (int k0 = 0; k0 < kKSEG; k0 += 16) {
        float4 av = *(const float4*)(aptr + k0);
        if (k0) __syncthreads();
        As[lk4+0][lrow] = av.x; As[lk4+1][lrow] = av.y;
        As[lk4+2][lrow] = av.z; As[lk4+3][lrow] = av.w;
        #pragma unroll
        for (int i = 0; i < 5; ++i) {
            int idx = t + 256 * i;
            int n = idx % 80;
            int k = idx / 80;
            Ws[k][n] = W[(size_t)n * kDI + kbase + k0 + k];
        }
        __syncthreads();
        #pragma unroll
        for (int k = 0; k < 16; ++k) {
            const float4 a4 = *(const float4*)&As[k][ci];
            const float aa[4] = {a4.x, a4.y, a4.z, a4.w};
            float ww[5];
            #pragma unroll
            for (int j = 0; j < 5; ++j) ww[j] = Ws[k][cj + j];
            #pragma unroll
            for (int i = 0; i < 4; ++i)
                #pragma unroll
                for (int j = 0; j < 5; ++j)
                    acc[i][j] = fmaf(aa[i], ww[j], acc[i][j]);
        }
    }

    float* pbase = part + ((size_t)blockIdx.y * kM) * kNX;
    #pragma unroll
    for (int i = 0; i < 4; ++i)
        #pragma unroll
        for (int j = 0; j < 5; ++j)
            pbase[(size_t)(m0 + ci + i) * kNX + cj + j] = acc[i][j];
}

__global__ __launch_bounds__(256) void xproj_reduce_kernel(
    const float* __restrict__ part, float* __restrict__ xdbl)
{
    int i = blockIdx.x * 256 + threadIdx.x;    // over kM*kNX
    float s = 0.f;
    #pragma unroll
    for (int k = 0; k < kKS; ++k) s += part[(size_t)k * kM * kNX + i];
    xdbl[i] = s;
}

// ---------------------------------------------------------------------------
// dt_proj v3: dt[m][n] = softplus(dot(xdbl[m][:48], Wd[n][:]) + b[n])
// Tiled 64x64, K=48 fully unrolled, transposed LDS tiles, 4x4 per thread.
__global__ __launch_bounds__(256) void dtproj3_kernel(
    const float* __restrict__ xdbl, const float* __restrict__ Wd,
    const float* __restrict__ bias, float* __restrict__ dt)
{
    __shared__ float As[48][68];   // As[k][m]
    __shared__ float Ws[48][68];   // Ws[k][n]
    const int t = threadIdx.x;
    const int m0 = blockIdx.x * 64;
    const int n0 = blockIdx.y * 64;

    // stage (transposed): 64 rows x 12 float4 = 768 float4 per matrix, 3/thread
    #pragma unroll
    for (int j = 0; j < 3; ++j) {
        int idx = t * 3 + j;
        int row = idx / 12, c4 = (idx % 12) * 4;
        float4 a = *(const float4*)&xdbl[(size_t)(m0 + row) * kNX + c4];
        As[c4+0][row] = a.x; As[c4+1][row] = a.y;
        As[c4+2][row] = a.z; As[c4+3][row] = a.w;
        float4 w = *(const float4*)&Wd[(size_t)(n0 + row) * kDTR + c4];
        Ws[c4+0][row] = w.x; Ws[c4+1][row] = w.y;
        Ws[c4+2][row] = w.z; Ws[c4+3][row] = w.w;
    }
    __syncthreads();

    const int ci = (t & 15) * 4;
    const int cj = (t >> 4) * 4;
    float acc[4][4] = {};
    #pragma unroll
    for (int k = 0; k < kDTR; ++k) {
        const float4 a4 = *(const float4*)&As[k][ci];
        const float4 w4 = *(const float4*)&Ws[k][cj];
        const float aa[4] = {a4.x, a4.y, a4.z, a4.w};
        const float ww[4] = {w4.x, w4.y, w4.z, w4.w};
        #pragma unroll
        for (int i = 0; i < 4; ++i)
            #pragma unroll
            for (int j = 0; j < 4; ++j)
                acc[i][j] = fmaf(aa[i], ww[j], acc[i][j]);
    }

    float4 bn = *(const float4*)&bias[n0 + cj];
    const float bb[4] = {bn.x, bn.y, bn.z, bn.w};
    #pragma unroll
    for (int i = 0; i < 4; ++i) {
        float4 o;
        float* op = (float*)&o;
        #pragma unroll
        for (int j = 0; j < 4; ++j) {
            float v = acc[i][j] + bb[j];
            op[j] = (v > 20.f) ? v : log1pf(__expf(v));
        }
        *(float4*)&dt[(size_t)(m0 + ci + i) * kDI + n0 + cj] = o;
    }
}

// ---------------------------------------------------------------------------
// causal depthwise conv (k=4) + SiLU, float4 over d
__global__ __launch_bounds__(256) void conv_silu_kernel(
    const float* __restrict__ xraw, const float* __restrict__ cw,
    const float* __restrict__ cb, float* __restrict__ xout)
{
    int i = blockIdx.x * 256 + threadIdx.x;     // over kM*kDI/4
    int d4 = i % (kDI / 4);
    int ml = i / (kDI / 4);
    int l = ml & (kL - 1);
    const int d = d4 * 4;
    float4 acc = *(const float4*)&cb[d];
    const float* base = xraw + (size_t)ml * kDI + d - 3 * (size_t)kDI;
    float4 w0 = *(const float4*)&cw[(d + 0) * 4];
    float4 w1 = *(const float4*)&cw[(d + 1) * 4];
    float4 w2 = *(const float4*)&cw[(d + 2) * 4];
    float4 w3 = *(const float4*)&cw[(d + 3) * 4];
    const float wj[4][4] = {{w0.x, w1.x, w2.x, w3.x}, {w0.y, w1.y, w2.y, w3.y},
                            {w0.z, w1.z, w2.z, w3.z}, {w0.w, w1.w, w2.w, w3.w}};
    #pragma unroll
    for (int j = 0; j < 4; ++j) {
        if (l - 3 + j >= 0) {
            float4 xv = *(const float4*)(base + (size_t)j * kDI);
            acc.x = fmaf(xv.x, wj[j][0], acc.x);
            acc.y = fmaf(xv.y, wj[j][1], acc.y);
            acc.z = fmaf(xv.z, wj[j][2], acc.z);
            acc.w = fmaf(xv.w, wj[j][3], acc.w);
        }
    }
    acc.x /= (1.f + __expf(-acc.x));
    acc.y /= (1.f + __expf(-acc.y));
    acc.z /= (1.f + __expf(-acc.z));
    acc.w /= (1.f + __expf(-acc.w));
    *(float4*)&xout[(size_t)ml * kDI + d] = acc;
}

// ---------------------------------------------------------------------------
// Selective scan v7: ZERO-LDS. 16 segments x 64 steps.
// Block = 256 threads = 64 channels x 4 state-quads (wave = one quad id).
// 16 states live in registers as f32x4; dt/u/g coalesced global loads
// (one per wave-step); B/C wave-uniform f32x4 global broadcasts (L2-hot).
constexpr int kNSEG = 16;
constexpr int kSEGL = kL / kNSEG;     // 64
constexpr int kP    = kB * kDI * 16;  // 98304 (b,d,s) tuples
constexpr float kLOG2E = 1.44269504089f;

__global__ __launch_bounds__(256, 6) void scan7_kernel(
    const float* __restrict__ u, const float* __restrict__ g,
    const float* __restrict__ dt, const float* __restrict__ xdbl,
    const float* __restrict__ A_log,
    float* __restrict__ PA, float* __restrict__ QA,
    float* __restrict__ accA, float* __restrict__ wcA,
    float* __restrict__ ugA)
{
    const int t = threadIdx.x;
    const int blk = blockIdx.x;          // grid = kB * 24 * kNSEG = 1536
    const int seg = blk & (kNSEG - 1);
    const int bd  = blk >> 4;            // 0..95
    const int b   = bd / 24;
    const int d0  = (bd % 24) * 64;
    const int c   = t & 63;              // channel within tile
    const int sq  = t >> 6;              // state-quad (wave id)
    const int d   = d0 + c;
    const int lb  = seg * kSEGL;

    // A constants for this thread's 4 states (pre-fold log2e)
    f32x4 Av;
    {
        float4 al = *(const float4*)&A_log[d * kDS + sq * 4];
        Av.x = -__expf(al.x) * kLOG2E;
        Av.y = -__expf(al.y) * kLOG2E;
        Av.z = -__expf(al.z) * kLOG2E;
        Av.w = -__expf(al.w) * kLOG2E;
    }

    const size_t base = ((size_t)b << 10) * kDI + (size_t)lb * kDI + d;
    const float* up  = u  + base;
    const float* gp  = g  + base;
    const float* dtp = dt + base;
    const float* bp  = xdbl + ((size_t)b << 10) * kNX + (size_t)lb * kNX
                            + kDTR + sq * 4;

    // prefetch step 0
    float nu = *up, ng = *gp, ndt = *dtp;
    f32x4 nB = *(const f32x4*)bp, nC = *(const f32x4*)(bp + 16);

    f32x4 h  = {0.f, 0.f, 0.f, 0.f};
    f32x4 cp = {1.f, 1.f, 1.f, 1.f};
    f32x4 acc = {0.f, 0.f, 0.f, 0.f};
    f32x4 wc  = {0.f, 0.f, 0.f, 0.f};
    float ug = 0.f;

    #pragma unroll 4
    for (int i = 0; i < kSEGL; ++i) {
        const float dtv = ndt, uv = nu, gv = ng;
        const f32x4 Bv = nB, Cv = nC;
        if (i < kSEGL - 1) {
            up += kDI; gp += kDI; dtp += kDI; bp += kNX;
            nu = *up; ng = *gp; ndt = *dtp;
            nB = *(const f32x4*)bp; nC = *(const f32x4*)(bp + 16);
        }
        const f32x4 pm = dtv * Av;
        f32x4 dA;
        dA.x = exp2f(pm.x); dA.y = exp2f(pm.y);
        dA.z = exp2f(pm.z); dA.w = exp2f(pm.w);
        const float dtu = dtv * uv;
        h  = dA * h + dtu * Bv;
        cp = cp * dA;
        const f32x4 cg = Cv * gv;
        acc = h * cg + acc;
        wc  = cp * cg + wc;
        ug  = fmaf(uv, gv, ug);
    }

    const int p = ((b * kDI + d) << 4) + sq * 4;
    const size_t o = (size_t)seg * kP + p;
    *(f32x4*)&PA[o]   = cp;
    *(f32x4*)&QA[o]   = h;
    *(f32x4*)&accA[o] = acc;
    *(f32x4*)&wcA[o]  = wc;
    if (sq == 0) ugA[(size_t)seg * (kB * kDI) + b * kDI + d] = ug;
}

// Pass 2: chain segments, reduce over states, add D*ug, write ysum.
__global__ __launch_bounds__(256) void scan_combine_kernel(
    const float* __restrict__ PA, const float* __restrict__ QA,
    const float* __restrict__ accA, const float* __restrict__ wcA,
    const float* __restrict__ ugA, const float* __restrict__ Dvec,
    float* __restrict__ ysum)
{
    const int p = blockIdx.x * 256 + threadIdx.x;   // 0..kP-1
    const int s = p & 15;
    const int bd = p >> 4;                          // b*kDI + d
    float h = 0.f, tot = 0.f;
    #pragma unroll
    for (int seg = 0; seg < kNSEG; ++seg) {
        const size_t o = (size_t)seg * kP + p;
        tot += accA[o] + h * wcA[o];
        h = fmaf(PA[o], h, QA[o]);
    }
    #pragma unroll
    for (int o2 = 1; o2 < 16; o2 <<= 1) tot += __shfl_xor(tot, o2, 64);
    if (s == 0) {
        float ug = 0.f;
        #pragma unroll
        for (int seg = 0; seg < kNSEG; ++seg)
            ug += ugA[(size_t)seg * (kB * kDI) + bd];
        ysum[bd] = tot + Dvec[bd % kDI] * ug;
    }
}

// ---------------------------------------------------------------------------
// out[b][j] = (1/L) * sum_d ysum[b][d] * Wout[j][d]
__global__ __launch_bounds__(256) void final_kernel(
    const float* __restrict__ ysum, const float* __restrict__ Wout,
    float* __restrict__ out)
{
    int gw = blockIdx.x * 4 + (threadIdx.x >> 6);
    int lane = threadIdx.x & 63;
    int b = gw / kDM;
    int j = gw - b * kDM;
    const float* yrow = ysum + (size_t)b * kDI;
    const float* wrow = Wout + (size_t)j * kDI;
    float acc = 0.f;
    for (int k = lane; k < kDI; k += 64) acc = fmaf(yrow[k], wrow[k], acc);
    #pragma unroll
    for (int o = 32; o; o >>= 1) acc += __shfl_xor(acc, o, 64);
    if (lane == 0) out[gw] = acc * (1.f / (float)kL);
}

// ---------------------------------------------------------------------------
extern "C" void kernel_launch(void* const* d_in, const int* in_sizes, int n_in,
                              void* d_out, int out_size, void* d_ws, size_t ws_size,
                              hipStream_t stream)
{
    const float* image_tokens = (const float*)d_in[0];
    const float* text_tokens  = (const float*)d_in[1];
    const float* W_txt        = (const float*)d_in[2];
    const float* b_txt        = (const float*)d_in[3];
    const float* in_proj_w    = (const float*)d_in[4];
    const float* conv_w       = (const float*)d_in[5];
    const float* conv_b       = (const float*)d_in[6];
    const float* x_proj_w     = (const float*)d_in[7];
    const float* dt_proj_w    = (const float*)d_in[8];
    const float* dt_proj_b    = (const float*)d_in[9];
    const float* A_log        = (const float*)d_in[10];
    const float* Dvec         = (const float*)d_in[11];
    const float* out_proj_w   = (const float*)d_in[12];
    float* out = (float*)d_out;

    // workspace layout (bytes, all 256B-aligned). Region lifetimes:
    //   dtreg: tokb+wb (until in_proj) -> part (xproj) -> dt (dtproj3..scan)
    //   xraw:  conv input (until conv) -> PA/QA/accA/wcA partials (scan..combine)
    char* p = (char*)d_ws;
    float* txt  = (float*)p;                      p += 12288;
    float* dtreg = (float*)p;                     p += (size_t)kM * kDI * 4;       // 25.2 MB
    float* xraw = (float*)p;                      p += (size_t)kM * kDI * 4;       // 25.2 MB
    float* gbuf = (float*)p;                      p += (size_t)kM * kDI * 4;       // 25.2 MB
    float* xbuf = (float*)p;                      p += (size_t)kM * kDI * 4;       // 25.2 MB
    float* xdbl = (float*)p;                      p += (size_t)kM * kNX * 4;       // 1.3 MB
    float* ysum = (float*)p;                      p += 32768;
    float* ugA  = (float*)p;                      p += (size_t)kNSEG * kB * kDI * 4; // 0.4 MB

    unsigned short* tokb = (unsigned short*)dtreg;          // 6.3 MB
    unsigned short* wb   = tokb + (size_t)kM * kDM;         // 4.7 MB
    float* part = dtreg;                                    // 10.5 MB (after in_proj)
    float* dtb  = dtreg;                                    // 25.2 MB (after xproj)
    float* PA   = xraw;                                     // partials
    float* QA   = PA + (size_t)kNSEG * kP;
    float* accA = QA + (size_t)kNSEG * kP;
    float* wcA  = accA + (size_t)kNSEG * kP;

    // 1) txt projection
    txt_kernel<<<dim3(kB * kDM / 4), dim3(256), 0, stream>>>(text_tokens, W_txt, b_txt, txt);

    // 2) tokens = bf16(image + txt)
    tokens_bf16_kernel<<<dim3(kM * kDM / 4 / 256), dim3(256), 0, stream>>>(image_tokens, txt, tokb);

    // 3) cast in_proj_w to bf16
    castw_kernel<<<dim3((2 * kDI * kDM / 4 + 255) / 256), dim3(256), 0, stream>>>(
        in_proj_w, wb, 2 * kDI * kDM / 4);

    // 4) in_proj (bf16 MFMA): x half -> xraw, z half -> g = silu(z)
    mfma_inproj_kernel<<<dim3(kM / 128, 2 * kDI / 128), dim3(256), 0, stream>>>(
        tokb, wb, xraw, gbuf);

    // 5) causal conv + silu (float4)
    conv_silu_kernel<<<dim3(kM * kDI / 4 / 256), dim3(256), 0, stream>>>(
        xraw, conv_w, conv_b, xbuf);

    // 6) x_proj split-K (part overlays dtreg; tokb/wb dead now)
    xproj_splitk_kernel<<<dim3(kM / 64, kKS), dim3(256), 0, stream>>>(xbuf, x_proj_w, part);
    xproj_reduce_kernel<<<dim3(kM * kNX / 256), dim3(256), 0, stream>>>(part, xdbl);

    // 7) dt_proj (tiled, K=48 unrolled) -> dtb (overlays dtreg; part dead now)
    dtproj3_kernel<<<dim3(kM / 64, kDI / 64), dim3(256), 0, stream>>>(
        xdbl, dt_proj_w, dt_proj_b, dtb);

    // 8) zero-LDS segmented scan + combine
    scan7_kernel<<<dim3(kB * 24 * kNSEG), dim3(256), 0, stream>>>(
        xbuf, gbuf, dtb, xdbl, A_log, PA, QA, accA, wcA, ugA);
    scan_combine_kernel<<<dim3(kP / 256), dim3(256), 0, stream>>>(
        PA, QA, accA, wcA, ugA, Dvec, ysum);

    // 9) out = (ysum/L) @ out_proj_w.T
    final_kernel<<<dim3(kB * kDM / 4), dim3(256), 0, stream>>>(ysum, out_proj_w, out);
}

// Round 10
// 229.264 us; speedup vs baseline: 1.3159x; 1.3159x over previous
//
#include <hip/hip_runtime.h>
#include <math.h>

// Problem constants
constexpr int kB   = 4;
constexpr int kL   = 1024;
constexpr int kDM  = 768;
constexpr int kDI  = 1536;   // 2*kDM
constexpr int kDS  = 16;     // D_STATE
constexpr int kDTR = 48;     // DT_RANK
constexpr int kNX  = 80;     // DTR + 2*DS
constexpr int kM   = kB * kL; // 4096
constexpr int kLTXT = 128;

typedef __attribute__((ext_vector_type(8))) short bf16x8;
typedef __attribute__((ext_vector_type(4))) float f32x4;

__device__ inline unsigned short f2bf(float f) {
    unsigned u = __float_as_uint(f);
    u = (u + 0x7FFFu + ((u >> 16) & 1u)) >> 16;   // RNE
    return (unsigned short)u;
}

__device__ __forceinline__ void gl2lds16(const unsigned short* g, unsigned short* l) {
    __builtin_amdgcn_global_load_lds(
        (const __attribute__((address_space(1))) unsigned int*)g,
        (__attribute__((address_space(3))) unsigned int*)l, 16, 0, 0);
}

// ---------------------------------------------------------------------------
// txt[b][j] = b_txt[j] + sum_k text_tokens[b,0,k] * W_txt[j,k]
__global__ __launch_bounds__(256) void txt_kernel(
    const float* __restrict__ text, const float* __restrict__ Wt,
    const float* __restrict__ bt, float* __restrict__ txt)
{
    int gw = blockIdx.x * 4 + (threadIdx.x >> 6);
    int lane = threadIdx.x & 63;
    int b = gw / kDM;
    int j = gw - b * kDM;
    const float* trow = text + (size_t)b * kLTXT * kDM;
    const float* wrow = Wt + (size_t)j * kDM;
    float acc = 0.f;
    for (int k = lane; k < kDM; k += 64) acc = fmaf(trow[k], wrow[k], acc);
    #pragma unroll
    for (int o = 32; o; o >>= 1) acc += __shfl_xor(acc, o, 64);
    if (lane == 0) txt[gw] = acc + bt[j];
}

// ---------------------------------------------------------------------------
// tokens_bf16[m][k] = bf16(image[m][k] + txt[m/1024][k])
__global__ __launch_bounds__(256) void tokens_bf16_kernel(
    const float* __restrict__ img, const float* __restrict__ txt,
    unsigned short* __restrict__ tok)
{
    int i = blockIdx.x * 256 + threadIdx.x;        // over kM*kDM/4
    float4 a = ((const float4*)img)[i];
    int m = i / (kDM / 4);
    int k4 = i - m * (kDM / 4);
    float4 tv = ((const float4*)(txt + (size_t)(m >> 10) * kDM))[k4];
    ushort4 o;
    o.x = f2bf(a.x + tv.x); o.y = f2bf(a.y + tv.y);
    o.z = f2bf(a.z + tv.z); o.w = f2bf(a.w + tv.w);
    ((ushort4*)tok)[i] = o;
}

// ---------------------------------------------------------------------------
// cast in_proj_w (f32, [3072][768]) -> bf16
__global__ __launch_bounds__(256) void castw_kernel(
    const float* __restrict__ w, unsigned short* __restrict__ o, int n4)
{
    int i = blockIdx.x * 256 + threadIdx.x;
    if (i >= n4) return;
    float4 a = ((const float4*)w)[i];
    ushort4 v;
    v.x = f2bf(a.x); v.y = f2bf(a.y); v.z = f2bf(a.z); v.w = f2bf(a.w);
    ((ushort4*)o)[i] = v;
}

// ---------------------------------------------------------------------------
// bf16 MFMA GEMM for in_proj (global_load_lds width-16, double-buffered LDS).
// M=4096, N=3072, K=768. BM=BN=128, BK=32, 256 threads (4 waves, 2x2).
// n<1536 -> xout; n>=1536 -> gout = silu(v)
__global__ __launch_bounds__(256) void mfma_inproj_kernel(
    const unsigned short* __restrict__ A, const unsigned short* __restrict__ W,
    float* __restrict__ xout, float* __restrict__ gout)
{
    __shared__ unsigned short Asm[2][128][32];
    __shared__ unsigned short Wsm[2][128][32];
    const int t = threadIdx.x;
    const int lane = t & 63;
    const int wv = t >> 6;             // wave 0..3
    const int wr = wv >> 1, wc = wv & 1;
    const int m0 = blockIdx.x * 128;
    const int n0 = blockIdx.y * 128;

    const int srow = lane >> 2;          // 0..15
    const int scol = (lane & 3) * 8;     // bf16 elem 0,8,16,24
    const unsigned short* agp  = A + (size_t)(m0 + wv * 32 + srow) * kDM + scol;
    const unsigned short* agp2 = agp + 16 * kDM;
    const unsigned short* wgp  = W + (size_t)(n0 + wv * 32 + srow) * kDM + scol;
    const unsigned short* wgp2 = wgp + 16 * kDM;

    auto stage = [&](int buf, int k0) {
        gl2lds16(agp  + k0, &Asm[buf][wv * 32][0]);
        gl2lds16(agp2 + k0, &Asm[buf][wv * 32 + 16][0]);
        gl2lds16(wgp  + k0, &Wsm[buf][wv * 32][0]);
        gl2lds16(wgp2 + k0, &Wsm[buf][wv * 32 + 16][0]);
    };

    f32x4 acc[4][4] = {};
    const int fr = lane & 15;
    const int fk = (lane >> 4) * 8;

    stage(0, 0);
    __syncthreads();

    int buf = 0;
    for (int k0 = 0; k0 < kDM; k0 += 32) {
        if (k0 + 32 < kDM) stage(buf ^ 1, k0 + 32);
        bf16x8 af[4], wf[4];
        #pragma unroll
        for (int i = 0; i < 4; ++i)
            af[i] = *(const bf16x8*)&Asm[buf][wr * 64 + i * 16 + fr][fk];
        #pragma unroll
        for (int j = 0; j < 4; ++j)
            wf[j] = *(const bf16x8*)&Wsm[buf][wc * 64 + j * 16 + fr][fk];
        #pragma unroll
        for (int i = 0; i < 4; ++i)
            #pragma unroll
            for (int j = 0; j < 4; ++j)
                acc[i][j] = __builtin_amdgcn_mfma_f32_16x16x32_bf16(af[i], wf[j], acc[i][j], 0, 0, 0);
        __syncthreads();
        buf ^= 1;
    }

    const int erow = (lane >> 4) * 4;
    const int ecol = lane & 15;
    #pragma unroll
    for (int i = 0; i < 4; ++i) {
        #pragma unroll
        for (int j = 0; j < 4; ++j) {
            const int gn = n0 + wc * 64 + j * 16 + ecol;
            #pragma unroll
            for (int q = 0; q < 4; ++q) {
                const int gm = m0 + wr * 64 + i * 16 + erow + q;
                float v = acc[i][j][q];
                if (gn < kDI) {
                    xout[(size_t)gm * kDI + gn] = v;
                } else {
                    gout[(size_t)gm * kDI + (gn - kDI)] = v / (1.f + __expf(-v));
                }
            }
        }
    }
}

// ---------------------------------------------------------------------------
// x_proj split-K: part[ks][m][n] = sum_{k in seg ks} x[m][k] * W[n][k]
constexpr int kKS   = 8;
constexpr int kKSEG = kDI / kKS;   // 192

__global__ __launch_bounds__(256) void xproj_splitk_kernel(
    const float* __restrict__ A, const float* __restrict__ W,
    float* __restrict__ part)
{
    __shared__ float As[16][68];
    __shared__ float Ws[16][84];
    const int t = threadIdx.x;
    const int m0 = blockIdx.x * 64;
    const int kbase = blockIdx.y * kKSEG;
    const int lrow = t >> 2, lk4 = (t & 3) << 2;
    const int ci = (t & 15) << 2;      // 4 rows
    const int cj = (t >> 4) * 5;       // 5 cols (16*5 = 80)
    float acc[4][5] = {};
    const float* aptr = A + (size_t)(m0 + lrow) * kDI + kbase + lk4;

    for (int k0 = 0; k0 < kKSEG; k0 += 16) {
        float4 av = *(const float4*)(aptr + k0);
        if (k0) __syncthreads();
        As[lk4+0][lrow] = av.x; As[lk4+1][lrow] = av.y;
        As[lk4+2][lrow] = av.z; As[lk4+3][lrow] = av.w;
        #pragma unroll
        for (int i = 0; i < 5; ++i) {
            int idx = t + 256 * i;
            int n = idx % 80;
            int k = idx / 80;
            Ws[k][n] = W[(size_t)n * kDI + kbase + k0 + k];
        }
        __syncthreads();
        #pragma unroll
        for (int k = 0; k < 16; ++k) {
            const float4 a4 = *(const float4*)&As[k][ci];
            const float aa[4] = {a4.x, a4.y, a4.z, a4.w};
            float ww[5];
            #pragma unroll
            for (int j = 0; j < 5; ++j) ww[j] = Ws[k][cj + j];
            #pragma unroll
            for (int i = 0; i < 4; ++i)
                #pragma unroll
                for (int j = 0; j < 5; ++j)
                    acc[i][j] = fmaf(aa[i], ww[j], acc[i][j]);
        }
    }

    float* pbase = part + ((size_t)blockIdx.y * kM) * kNX;
    #pragma unroll
    for (int i = 0; i < 4; ++i)
        #pragma unroll
        for (int j = 0; j < 5; ++j)
            pbase[(size_t)(m0 + ci + i) * kNX + cj + j] = acc[i][j];
}

__global__ __launch_bounds__(256) void xproj_reduce_kernel(
    const float* __restrict__ part, float* __restrict__ xdbl)
{
    int i = blockIdx.x * 256 + threadIdx.x;    // over kM*kNX
    float s = 0.f;
    #pragma unroll
    for (int k = 0; k < kKS; ++k) s += part[(size_t)k * kM * kNX + i];
    xdbl[i] = s;
}

// ---------------------------------------------------------------------------
// dt_proj v3: dt[m][n] = softplus(dot(xdbl[m][:48], Wd[n][:]) + b[n])
// Tiled 64x64, K=48 fully unrolled, transposed LDS tiles, 4x4 per thread.
__global__ __launch_bounds__(256) void dtproj3_kernel(
    const float* __restrict__ xdbl, const float* __restrict__ Wd,
    const float* __restrict__ bias, float* __restrict__ dt)
{
    __shared__ float As[48][68];   // As[k][m]
    __shared__ float Ws[48][68];   // Ws[k][n]
    const int t = threadIdx.x;
    const int m0 = blockIdx.x * 64;
    const int n0 = blockIdx.y * 64;

    #pragma unroll
    for (int j = 0; j < 3; ++j) {
        int idx = t * 3 + j;
        int row = idx / 12, c4 = (idx % 12) * 4;
        float4 a = *(const float4*)&xdbl[(size_t)(m0 + row) * kNX + c4];
        As[c4+0][row] = a.x; As[c4+1][row] = a.y;
        As[c4+2][row] = a.z; As[c4+3][row] = a.w;
        float4 w = *(const float4*)&Wd[(size_t)(n0 + row) * kDTR + c4];
        Ws[c4+0][row] = w.x; Ws[c4+1][row] = w.y;
        Ws[c4+2][row] = w.z; Ws[c4+3][row] = w.w;
    }
    __syncthreads();

    const int ci = (t & 15) * 4;
    const int cj = (t >> 4) * 4;
    float acc[4][4] = {};
    #pragma unroll
    for (int k = 0; k < kDTR; ++k) {
        const float4 a4 = *(const float4*)&As[k][ci];
        const float4 w4 = *(const float4*)&Ws[k][cj];
        const float aa[4] = {a4.x, a4.y, a4.z, a4.w};
        const float ww[4] = {w4.x, w4.y, w4.z, w4.w};
        #pragma unroll
        for (int i = 0; i < 4; ++i)
            #pragma unroll
            for (int j = 0; j < 4; ++j)
                acc[i][j] = fmaf(aa[i], ww[j], acc[i][j]);
    }

    float4 bn = *(const float4*)&bias[n0 + cj];
    const float bb[4] = {bn.x, bn.y, bn.z, bn.w};
    #pragma unroll
    for (int i = 0; i < 4; ++i) {
        float4 o;
        float* op = (float*)&o;
        #pragma unroll
        for (int j = 0; j < 4; ++j) {
            float v = acc[i][j] + bb[j];
            op[j] = (v > 20.f) ? v : log1pf(__expf(v));
        }
        *(float4*)&dt[(size_t)(m0 + ci + i) * kDI + n0 + cj] = o;
    }
}

// ---------------------------------------------------------------------------
// causal depthwise conv (k=4) + SiLU, float4 over d
__global__ __launch_bounds__(256) void conv_silu_kernel(
    const float* __restrict__ xraw, const float* __restrict__ cw,
    const float* __restrict__ cb, float* __restrict__ xout)
{
    int i = blockIdx.x * 256 + threadIdx.x;     // over kM*kDI/4
    int d4 = i % (kDI / 4);
    int ml = i / (kDI / 4);
    int l = ml & (kL - 1);
    const int d = d4 * 4;
    float4 acc = *(const float4*)&cb[d];
    const float* base = xraw + (size_t)ml * kDI + d - 3 * (size_t)kDI;
    float4 w0 = *(const float4*)&cw[(d + 0) * 4];
    float4 w1 = *(const float4*)&cw[(d + 1) * 4];
    float4 w2 = *(const float4*)&cw[(d + 2) * 4];
    float4 w3 = *(const float4*)&cw[(d + 3) * 4];
    const float wj[4][4] = {{w0.x, w1.x, w2.x, w3.x}, {w0.y, w1.y, w2.y, w3.y},
                            {w0.z, w1.z, w2.z, w3.z}, {w0.w, w1.w, w2.w, w3.w}};
    #pragma unroll
    for (int j = 0; j < 4; ++j) {
        if (l - 3 + j >= 0) {
            float4 xv = *(const float4*)(base + (size_t)j * kDI);
            acc.x = fmaf(xv.x, wj[j][0], acc.x);
            acc.y = fmaf(xv.y, wj[j][1], acc.y);
            acc.z = fmaf(xv.z, wj[j][2], acc.z);
            acc.w = fmaf(xv.w, wj[j][3], acc.w);
        }
    }
    acc.x /= (1.f + __expf(-acc.x));
    acc.y /= (1.f + __expf(-acc.y));
    acc.z /= (1.f + __expf(-acc.z));
    acc.w /= (1.f + __expf(-acc.w));
    *(float4*)&xout[(size_t)ml * kDI + d] = acc;
}

// ---------------------------------------------------------------------------
// Selective scan v8: LDS-staged chunks + 4 states/thread in registers.
// Block = 256 threads = 64 channels x 4 state-quads (sq = wave id).
// 16 segments x 64 steps; per segment: 2 chunks of 32 steps, register
// double-buffer prefetch. Per wave-step: 3 b32 (dt/u/g) + 2 uniform b128
// (B/C) LDS reads covering 256 state-steps.
constexpr int kNSEG = 16;
constexpr int kSEGL = kL / kNSEG;     // 64
constexpr int kCT   = 32;             // steps per chunk
constexpr int kP    = kB * kDI * 16;  // 98304 (b,d,s) tuples
constexpr float kLOG2E = 1.44269504089f;

__global__ __launch_bounds__(256, 4) void scan8_kernel(
    const float* __restrict__ u, const float* __restrict__ g,
    const float* __restrict__ dt, const float* __restrict__ xdbl,
    const float* __restrict__ A_log,
    float* __restrict__ PA, float* __restrict__ QA,
    float* __restrict__ accA, float* __restrict__ wcA,
    float* __restrict__ ugA)
{
    __shared__ float uS [kCT][64];     // 8 KB
    __shared__ float gS [kCT][64];     // 8 KB
    __shared__ float dtS[kCT][64];     // 8 KB
    __shared__ float bcS[kCT][34];     // B|C (32 used) + pad   4.25 KB
    const int t = threadIdx.x;
    const int blk = blockIdx.x;          // grid = 96 * kNSEG = 1536
    const int seg = blk & (kNSEG - 1);
    const int bd  = blk >> 4;            // 0..95
    const int b   = bd / 24;
    const int d0  = (bd % 24) * 64;
    const int c   = t & 63;              // channel
    const int sq  = t >> 6;              // state-quad (wave-uniform)
    const int d   = d0 + c;
    const int lb  = seg * kSEGL;

    // A constants (pre-fold log2e)
    f32x4 Av;
    {
        float4 al = *(const float4*)&A_log[d * kDS + sq * 4];
        Av.x = -__expf(al.x) * kLOG2E;
        Av.y = -__expf(al.y) * kLOG2E;
        Av.z = -__expf(al.z) * kLOG2E;
        Av.w = -__expf(al.w) * kLOG2E;
    }

    // staging maps: u/g/dt 32x64 floats = 512 f4, 2/thread; bc 32x32 = 256 f4
    const float* u_base  = u  + ((size_t)b << 10) * kDI + d0;
    const float* g_base  = g  + ((size_t)b << 10) * kDI + d0;
    const float* dt_base = dt + ((size_t)b << 10) * kDI + d0;
    const float* bc_base = xdbl + ((size_t)b << 10) * kNX + kDTR;
    const int rb = t >> 3, cb = (t & 7) * 4;

    float4 ru[2], rg[2], rdt[2], rbc;
    auto load_chunk = [&](int l0) {
        #pragma unroll
        for (int j = 0; j < 2; ++j) {
            int idx = t + 256 * j;
            int row = idx >> 4, col = (idx & 15) * 4;
            ru [j] = *(const float4*)(u_base  + (size_t)(l0 + row) * kDI + col);
            rg [j] = *(const float4*)(g_base  + (size_t)(l0 + row) * kDI + col);
            rdt[j] = *(const float4*)(dt_base + (size_t)(l0 + row) * kDI + col);
        }
        rbc = *(const float4*)(bc_base + (size_t)(l0 + rb) * kNX + cb);
    };
    auto store_chunk = [&]() {
        #pragma unroll
        for (int j = 0; j < 2; ++j) {
            int idx = t + 256 * j;
            int row = idx >> 4, col = (idx & 15) * 4;
            *(float4*)&uS [row][col] = ru [j];
            *(float4*)&gS [row][col] = rg [j];
            *(float4*)&dtS[row][col] = rdt[j];
        }
        *(float4*)&bcS[rb][cb] = rbc;
    };

    f32x4 h   = {0.f, 0.f, 0.f, 0.f};
    f32x4 cp  = {1.f, 1.f, 1.f, 1.f};
    f32x4 acc = {0.f, 0.f, 0.f, 0.f};
    f32x4 wc  = {0.f, 0.f, 0.f, 0.f};
    float ug = 0.f;

    load_chunk(lb);
    store_chunk();
    __syncthreads();

    #pragma unroll
    for (int ck = 0; ck < kSEGL / kCT; ++ck) {
        if (ck + 1 < kSEGL / kCT) load_chunk(lb + (ck + 1) * kCT);
        #pragma unroll 8
        for (int i = 0; i < kCT; ++i) {
            const float dtv = dtS[i][c];
            const float uv  = uS [i][c];
            const float gv  = gS [i][c];
            const f32x4 Bv = *(const f32x4*)&bcS[i][sq * 4];        // uniform
            const f32x4 Cv = *(const f32x4*)&bcS[i][16 + sq * 4];   // uniform
            const f32x4 pm = dtv * Av;
            f32x4 dA;
            dA.x = exp2f(pm.x); dA.y = exp2f(pm.y);
            dA.z = exp2f(pm.z); dA.w = exp2f(pm.w);
            const float dtu = dtv * uv;
            h  = dA * h + dtu * Bv;
            cp = cp * dA;
            const f32x4 cg = Cv * gv;
            acc = h * cg + acc;
            wc  = cp * cg + wc;
            ug  = fmaf(uv, gv, ug);
        }
        if (ck + 1 < kSEGL / kCT) {
            __syncthreads();     // everyone done reading this chunk
            store_chunk();
            __syncthreads();
        }
    }

    const int p = ((b * kDI + d) << 4) + sq * 4;
    const size_t o = (size_t)seg * kP + p;
    *(f32x4*)&PA[o]   = cp;
    *(f32x4*)&QA[o]   = h;
    *(f32x4*)&accA[o] = acc;
    *(f32x4*)&wcA[o]  = wc;
    if (sq == 0) ugA[(size_t)seg * (kB * kDI) + b * kDI + d] = ug;
}

// Pass 2: chain segments, reduce over states, add D*ug, write ysum.
__global__ __launch_bounds__(256) void scan_combine_kernel(
    const float* __restrict__ PA, const float* __restrict__ QA,
    const float* __restrict__ accA, const float* __restrict__ wcA,
    const float* __restrict__ ugA, const float* __restrict__ Dvec,
    float* __restrict__ ysum)
{
    const int p = blockIdx.x * 256 + threadIdx.x;   // 0..kP-1
    const int s = p & 15;
    const int bd = p >> 4;                          // b*kDI + d
    float h = 0.f, tot = 0.f;
    #pragma unroll
    for (int seg = 0; seg < kNSEG; ++seg) {
        const size_t o = (size_t)seg * kP + p;
        tot += accA[o] + h * wcA[o];
        h = fmaf(PA[o], h, QA[o]);
    }
    #pragma unroll
    for (int o2 = 1; o2 < 16; o2 <<= 1) tot += __shfl_xor(tot, o2, 64);
    if (s == 0) {
        float ug = 0.f;
        #pragma unroll
        for (int seg = 0; seg < kNSEG; ++seg)
            ug += ugA[(size_t)seg * (kB * kDI) + bd];
        ysum[bd] = tot + Dvec[bd % kDI] * ug;
    }
}

// ---------------------------------------------------------------------------
// out[b][j] = (1/L) * sum_d ysum[b][d] * Wout[j][d]
__global__ __launch_bounds__(256) void final_kernel(
    const float* __restrict__ ysum, const float* __restrict__ Wout,
    float* __restrict__ out)
{
    int gw = blockIdx.x * 4 + (threadIdx.x >> 6);
    int lane = threadIdx.x & 63;
    int b = gw / kDM;
    int j = gw - b * kDM;
    const float* yrow = ysum + (size_t)b * kDI;
    const float* wrow = Wout + (size_t)j * kDI;
    float acc = 0.f;
    for (int k = lane; k < kDI; k += 64) acc = fmaf(yrow[k], wrow[k], acc);
    #pragma unroll
    for (int o = 32; o; o >>= 1) acc += __shfl_xor(acc, o, 64);
    if (lane == 0) out[gw] = acc * (1.f / (float)kL);
}

// ---------------------------------------------------------------------------
extern "C" void kernel_launch(void* const* d_in, const int* in_sizes, int n_in,
                              void* d_out, int out_size, void* d_ws, size_t ws_size,
                              hipStream_t stream)
{
    const float* image_tokens = (const float*)d_in[0];
    const float* text_tokens  = (const float*)d_in[1];
    const float* W_txt        = (const float*)d_in[2];
    const float* b_txt        = (const float*)d_in[3];
    const float* in_proj_w    = (const float*)d_in[4];
    const float* conv_w       = (const float*)d_in[5];
    const float* conv_b       = (const float*)d_in[6];
    const float* x_proj_w     = (const float*)d_in[7];
    const float* dt_proj_w    = (const float*)d_in[8];
    const float* dt_proj_b    = (const float*)d_in[9];
    const float* A_log        = (const float*)d_in[10];
    const float* Dvec         = (const float*)d_in[11];
    const float* out_proj_w   = (const float*)d_in[12];
    float* out = (float*)d_out;

    // workspace layout (bytes, all 256B-aligned). Region lifetimes:
    //   dtreg: tokb+wb (until in_proj) -> part (xproj) -> dt (dtproj3..scan)
    //   xraw:  conv input (until conv) -> PA/QA/accA/wcA partials (scan..combine)
    char* p = (char*)d_ws;
    float* txt  = (float*)p;                      p += 12288;
    float* dtreg = (float*)p;                     p += (size_t)kM * kDI * 4;       // 25.2 MB
    float* xraw = (float*)p;                      p += (size_t)kM * kDI * 4;       // 25.2 MB
    float* gbuf = (float*)p;                      p += (size_t)kM * kDI * 4;       // 25.2 MB
    float* xbuf = (float*)p;                      p += (size_t)kM * kDI * 4;       // 25.2 MB
    float* xdbl = (float*)p;                      p += (size_t)kM * kNX * 4;       // 1.3 MB
    float* ysum = (float*)p;                      p += 32768;
    float* ugA  = (float*)p;                      p += (size_t)kNSEG * kB * kDI * 4; // 0.4 MB

    unsigned short* tokb = (unsigned short*)dtreg;          // 6.3 MB
    unsigned short* wb   = tokb + (size_t)kM * kDM;         // 4.7 MB
    float* part = dtreg;                                    // 10.5 MB (after in_proj)
    float* dtb  = dtreg;                                    // 25.2 MB (after xproj)
    float* PA   = xraw;                                     // partials
    float* QA   = PA + (size_t)kNSEG * kP;
    float* accA = QA + (size_t)kNSEG * kP;
    float* wcA  = accA + (size_t)kNSEG * kP;

    // 1) txt projection
    txt_kernel<<<dim3(kB * kDM / 4), dim3(256), 0, stream>>>(text_tokens, W_txt, b_txt, txt);

    // 2) tokens = bf16(image + txt)
    tokens_bf16_kernel<<<dim3(kM * kDM / 4 / 256), dim3(256), 0, stream>>>(image_tokens, txt, tokb);

    // 3) cast in_proj_w to bf16
    castw_kernel<<<dim3((2 * kDI * kDM / 4 + 255) / 256), dim3(256), 0, stream>>>(
        in_proj_w, wb, 2 * kDI * kDM / 4);

    // 4) in_proj (bf16 MFMA): x half -> xraw, z half -> g = silu(z)
    mfma_inproj_kernel<<<dim3(kM / 128, 2 * kDI / 128), dim3(256), 0, stream>>>(
        tokb, wb, xraw, gbuf);

    // 5) causal conv + silu (float4)
    conv_silu_kernel<<<dim3(kM * kDI / 4 / 256), dim3(256), 0, stream>>>(
        xraw, conv_w, conv_b, xbuf);

    // 6) x_proj split-K (part overlays dtreg; tokb/wb dead now)
    xproj_splitk_kernel<<<dim3(kM / 64, kKS), dim3(256), 0, stream>>>(xbuf, x_proj_w, part);
    xproj_reduce_kernel<<<dim3(kM * kNX / 256), dim3(256), 0, stream>>>(part, xdbl);

    // 7) dt_proj (tiled, K=48 unrolled) -> dtb (overlays dtreg; part dead now)
    dtproj3_kernel<<<dim3(kM / 64, kDI / 64), dim3(256), 0, stream>>>(
        xdbl, dt_proj_w, dt_proj_b, dtb);

    // 8) LDS-staged register-state segmented scan + combine
    scan8_kernel<<<dim3(kB * 24 * kNSEG), dim3(256), 0, stream>>>(
        xbuf, gbuf, dtb, xdbl, A_log, PA, QA, accA, wcA, ugA);
    scan_combine_kernel<<<dim3(kP / 256), dim3(256), 0, stream>>>(
        PA, QA, accA, wcA, ugA, Dvec, ysum);

    // 9) out = (ysum/L) @ out_proj_w.T
    final_kernel<<<dim3(kB * kDM / 4), dim3(256), 0, stream>>>(ysum, out_proj_w, out);
}

// Round 11
// 207.103 us; speedup vs baseline: 1.4567x; 1.1070x over previous
//
#include <hip/hip_runtime.h>
#include <math.h>

// Problem constants
constexpr int kB   = 4;
constexpr int kL   = 1024;
constexpr int kDM  = 768;
constexpr int kDI  = 1536;   // 2*kDM
constexpr int kDS  = 16;     // D_STATE
constexpr int kDTR = 48;     // DT_RANK
constexpr int kNX  = 80;     // DTR + 2*DS
constexpr int kM   = kB * kL; // 4096
constexpr int kLTXT = 128;

typedef __attribute__((ext_vector_type(8))) short bf16x8;
typedef __attribute__((ext_vector_type(4))) float f32x4;

__device__ inline unsigned short f2bf(float f) {
    unsigned u = __float_as_uint(f);
    u = (u + 0x7FFFu + ((u >> 16) & 1u)) >> 16;   // RNE
    return (unsigned short)u;
}

__device__ __forceinline__ void gl2lds16(const unsigned short* g, unsigned short* l) {
    __builtin_amdgcn_global_load_lds(
        (const __attribute__((address_space(1))) unsigned int*)g,
        (__attribute__((address_space(3))) unsigned int*)l, 16, 0, 0);
}

// ---------------------------------------------------------------------------
// txt[b][j] = b_txt[j] + sum_k text_tokens[b,0,k] * W_txt[j,k]
__global__ __launch_bounds__(256) void txt_kernel(
    const float* __restrict__ text, const float* __restrict__ Wt,
    const float* __restrict__ bt, float* __restrict__ txt)
{
    int gw = blockIdx.x * 4 + (threadIdx.x >> 6);
    int lane = threadIdx.x & 63;
    int b = gw / kDM;
    int j = gw - b * kDM;
    const float* trow = text + (size_t)b * kLTXT * kDM;
    const float* wrow = Wt + (size_t)j * kDM;
    float acc = 0.f;
    for (int k = lane; k < kDM; k += 64) acc = fmaf(trow[k], wrow[k], acc);
    #pragma unroll
    for (int o = 32; o; o >>= 1) acc += __shfl_xor(acc, o, 64);
    if (lane == 0) txt[gw] = acc + bt[j];
}

// ---------------------------------------------------------------------------
// tokens_bf16[m][k] = bf16(image[m][k] + txt[m/1024][k])
__global__ __launch_bounds__(256) void tokens_bf16_kernel(
    const float* __restrict__ img, const float* __restrict__ txt,
    unsigned short* __restrict__ tok)
{
    int i = blockIdx.x * 256 + threadIdx.x;        // over kM*kDM/4
    float4 a = ((const float4*)img)[i];
    int m = i / (kDM / 4);
    int k4 = i - m * (kDM / 4);
    float4 tv = ((const float4*)(txt + (size_t)(m >> 10) * kDM))[k4];
    ushort4 o;
    o.x = f2bf(a.x + tv.x); o.y = f2bf(a.y + tv.y);
    o.z = f2bf(a.z + tv.z); o.w = f2bf(a.w + tv.w);
    ((ushort4*)tok)[i] = o;
}

// ---------------------------------------------------------------------------
// cast in_proj_w (f32, [3072][768]) -> bf16
__global__ __launch_bounds__(256) void castw_kernel(
    const float* __restrict__ w, unsigned short* __restrict__ o, int n4)
{
    int i = blockIdx.x * 256 + threadIdx.x;
    if (i >= n4) return;
    float4 a = ((const float4*)w)[i];
    ushort4 v;
    v.x = f2bf(a.x); v.y = f2bf(a.y); v.z = f2bf(a.z); v.w = f2bf(a.w);
    ((ushort4*)o)[i] = v;
}

// ---------------------------------------------------------------------------
// bf16 MFMA GEMM for in_proj (global_load_lds width-16, double-buffered LDS).
// M=4096, N=3072, K=768. BM=BN=128, BK=32, 256 threads (4 waves, 2x2).
// n<1536 -> xout; n>=1536 -> gout = silu(v)
__global__ __launch_bounds__(256) void mfma_inproj_kernel(
    const unsigned short* __restrict__ A, const unsigned short* __restrict__ W,
    float* __restrict__ xout, float* __restrict__ gout)
{
    __shared__ unsigned short Asm[2][128][32];
    __shared__ unsigned short Wsm[2][128][32];
    const int t = threadIdx.x;
    const int lane = t & 63;
    const int wv = t >> 6;             // wave 0..3
    const int wr = wv >> 1, wc = wv & 1;
    const int m0 = blockIdx.x * 128;
    const int n0 = blockIdx.y * 128;

    const int srow = lane >> 2;          // 0..15
    const int scol = (lane & 3) * 8;     // bf16 elem 0,8,16,24
    const unsigned short* agp  = A + (size_t)(m0 + wv * 32 + srow) * kDM + scol;
    const unsigned short* agp2 = agp + 16 * kDM;
    const unsigned short* wgp  = W + (size_t)(n0 + wv * 32 + srow) * kDM + scol;
    const unsigned short* wgp2 = wgp + 16 * kDM;

    auto stage = [&](int buf, int k0) {
        gl2lds16(agp  + k0, &Asm[buf][wv * 32][0]);
        gl2lds16(agp2 + k0, &Asm[buf][wv * 32 + 16][0]);
        gl2lds16(wgp  + k0, &Wsm[buf][wv * 32][0]);
        gl2lds16(wgp2 + k0, &Wsm[buf][wv * 32 + 16][0]);
    };

    f32x4 acc[4][4] = {};
    const int fr = lane & 15;
    const int fk = (lane >> 4) * 8;

    stage(0, 0);
    __syncthreads();

    int buf = 0;
    for (int k0 = 0; k0 < kDM; k0 += 32) {
        if (k0 + 32 < kDM) stage(buf ^ 1, k0 + 32);
        bf16x8 af[4], wf[4];
        #pragma unroll
        for (int i = 0; i < 4; ++i)
            af[i] = *(const bf16x8*)&Asm[buf][wr * 64 + i * 16 + fr][fk];
        #pragma unroll
        for (int j = 0; j < 4; ++j)
            wf[j] = *(const bf16x8*)&Wsm[buf][wc * 64 + j * 16 + fr][fk];
        #pragma unroll
        for (int i = 0; i < 4; ++i)
            #pragma unroll
            for (int j = 0; j < 4; ++j)
                acc[i][j] = __builtin_amdgcn_mfma_f32_16x16x32_bf16(af[i], wf[j], acc[i][j], 0, 0, 0);
        __syncthreads();
        buf ^= 1;
    }

    const int erow = (lane >> 4) * 4;
    const int ecol = lane & 15;
    #pragma unroll
    for (int i = 0; i < 4; ++i) {
        #pragma unroll
        for (int j = 0; j < 4; ++j) {
            const int gn = n0 + wc * 64 + j * 16 + ecol;
            #pragma unroll
            for (int q = 0; q < 4; ++q) {
                const int gm = m0 + wr * 64 + i * 16 + erow + q;
                float v = acc[i][j][q];
                if (gn < kDI) {
                    xout[(size_t)gm * kDI + gn] = v;
                } else {
                    gout[(size_t)gm * kDI + (gn - kDI)] = v / (1.f + __expf(-v));
                }
            }
        }
    }
}

// ---------------------------------------------------------------------------
// x_proj split-K: part[ks][m][n] = sum_{k in seg ks} x[m][k] * W[n][k]
constexpr int kKS   = 8;
constexpr int kKSEG = kDI / kKS;   // 192

__global__ __launch_bounds__(256) void xproj_splitk_kernel(
    const float* __restrict__ A, const float* __restrict__ W,
    float* __restrict__ part)
{
    __shared__ float As[16][68];
    __shared__ float Ws[16][84];
    const int t = threadIdx.x;
    const int m0 = blockIdx.x * 64;
    const int kbase = blockIdx.y * kKSEG;
    const int lrow = t >> 2, lk4 = (t & 3) << 2;
    const int ci = (t & 15) << 2;      // 4 rows
    const int cj = (t >> 4) * 5;       // 5 cols (16*5 = 80)
    float acc[4][5] = {};
    const float* aptr = A + (size_t)(m0 + lrow) * kDI + kbase + lk4;

    for (int k0 = 0; k0 < kKSEG; k0 += 16) {
        float4 av = *(const float4*)(aptr + k0);
        if (k0) __syncthreads();
        As[lk4+0][lrow] = av.x; As[lk4+1][lrow] = av.y;
        As[lk4+2][lrow] = av.z; As[lk4+3][lrow] = av.w;
        #pragma unroll
        for (int i = 0; i < 5; ++i) {
            int idx = t + 256 * i;
            int n = idx % 80;
            int k = idx / 80;
            Ws[k][n] = W[(size_t)n * kDI + kbase + k0 + k];
        }
        __syncthreads();
        #pragma unroll
        for (int k = 0; k < 16; ++k) {
            const float4 a4 = *(const float4*)&As[k][ci];
            const float aa[4] = {a4.x, a4.y, a4.z, a4.w};
            float ww[5];
            #pragma unroll
            for (int j = 0; j < 5; ++j) ww[j] = Ws[k][cj + j];
            #pragma unroll
            for (int i = 0; i < 4; ++i)
                #pragma unroll
                for (int j = 0; j < 5; ++j)
                    acc[i][j] = fmaf(aa[i], ww[j], acc[i][j]);
        }
    }

    float* pbase = part + ((size_t)blockIdx.y * kM) * kNX;
    #pragma unroll
    for (int i = 0; i < 4; ++i)
        #pragma unroll
        for (int j = 0; j < 5; ++j)
            pbase[(size_t)(m0 + ci + i) * kNX + cj + j] = acc[i][j];
}

__global__ __launch_bounds__(256) void xproj_reduce_kernel(
    const float* __restrict__ part, float* __restrict__ xdbl)
{
    int i = blockIdx.x * 256 + threadIdx.x;    // over kM*kNX
    float s = 0.f;
    #pragma unroll
    for (int k = 0; k < kKS; ++k) s += part[(size_t)k * kM * kNX + i];
    xdbl[i] = s;
}

// ---------------------------------------------------------------------------
// dt_proj v4 = round-2 proven gemm structure (VGPR ~36, no spill).
// dt[m][n] = softplus(sum_k xdbl[m][k]*Wd[n][k] + b[n]); K=48, BK=16.
// BM=BN=64, 256 threads, 4x4 per thread. Grid (64, 24).
__global__ __launch_bounds__(256) void dtproj_gemm_kernel(
    const float* __restrict__ A, const float* __restrict__ W,
    const float* __restrict__ bias, float* __restrict__ dt)
{
    __shared__ float As[16][68];
    __shared__ float Ws[16][68];
    const int t = threadIdx.x;
    const int m0 = blockIdx.x * 64;
    const int n0 = blockIdx.y * 64;
    const int lrow = t >> 2;          // 0..63
    const int lk4  = (t & 3) << 2;    // 0,4,8,12
    const int ci   = (t & 15) << 2;
    const int cj   = (t >> 4) << 2;
    float acc[4][4] = {};
    const float* aptr = A + (size_t)(m0 + lrow) * kNX + lk4;
    const float* wptr = W + (size_t)(n0 + lrow) * kDTR + lk4;

    for (int k0 = 0; k0 < kDTR; k0 += 16) {
        float4 av = *(const float4*)(aptr + k0);
        float4 wv = *(const float4*)(wptr + k0);
        if (k0) __syncthreads();
        As[lk4+0][lrow] = av.x; As[lk4+1][lrow] = av.y;
        As[lk4+2][lrow] = av.z; As[lk4+3][lrow] = av.w;
        Ws[lk4+0][lrow] = wv.x; Ws[lk4+1][lrow] = wv.y;
        Ws[lk4+2][lrow] = wv.z; Ws[lk4+3][lrow] = wv.w;
        __syncthreads();
        #pragma unroll
        for (int k = 0; k < 16; ++k) {
            const float4 a4 = *(const float4*)&As[k][ci];
            const float4 w4 = *(const float4*)&Ws[k][cj];
            const float aa[4] = {a4.x, a4.y, a4.z, a4.w};
            const float ww[4] = {w4.x, w4.y, w4.z, w4.w};
            #pragma unroll
            for (int i = 0; i < 4; ++i)
                #pragma unroll
                for (int j = 0; j < 4; ++j)
                    acc[i][j] = fmaf(aa[i], ww[j], acc[i][j]);
        }
    }

    #pragma unroll
    for (int i = 0; i < 4; ++i) {
        const int gm = m0 + ci + i;
        #pragma unroll
        for (int j = 0; j < 4; ++j) {
            const int gn = n0 + cj + j;
            float v = acc[i][j] + bias[gn];
            v = (v > 20.f) ? v : log1pf(__expf(v));   // softplus
            dt[(size_t)gm * kDI + gn] = v;
        }
    }
}

// ---------------------------------------------------------------------------
// causal depthwise conv (k=4) + SiLU, float4 over d
__global__ __launch_bounds__(256) void conv_silu_kernel(
    const float* __restrict__ xraw, const float* __restrict__ cw,
    const float* __restrict__ cb, float* __restrict__ xout)
{
    int i = blockIdx.x * 256 + threadIdx.x;     // over kM*kDI/4
    int d4 = i % (kDI / 4);
    int ml = i / (kDI / 4);
    int l = ml & (kL - 1);
    const int d = d4 * 4;
    float4 acc = *(const float4*)&cb[d];
    const float* base = xraw + (size_t)ml * kDI + d - 3 * (size_t)kDI;
    float4 w0 = *(const float4*)&cw[(d + 0) * 4];
    float4 w1 = *(const float4*)&cw[(d + 1) * 4];
    float4 w2 = *(const float4*)&cw[(d + 2) * 4];
    float4 w3 = *(const float4*)&cw[(d + 3) * 4];
    const float wj[4][4] = {{w0.x, w1.x, w2.x, w3.x}, {w0.y, w1.y, w2.y, w3.y},
                            {w0.z, w1.z, w2.z, w3.z}, {w0.w, w1.w, w2.w, w3.w}};
    #pragma unroll
    for (int j = 0; j < 4; ++j) {
        if (l - 3 + j >= 0) {
            float4 xv = *(const float4*)(base + (size_t)j * kDI);
            acc.x = fmaf(xv.x, wj[j][0], acc.x);
            acc.y = fmaf(xv.y, wj[j][1], acc.y);
            acc.z = fmaf(xv.z, wj[j][2], acc.z);
            acc.w = fmaf(xv.w, wj[j][3], acc.w);
        }
    }
    acc.x /= (1.f + __expf(-acc.x));
    acc.y /= (1.f + __expf(-acc.y));
    acc.z /= (1.f + __expf(-acc.z));
    acc.w /= (1.f + __expf(-acc.w));
    *(float4*)&xout[(size_t)ml * kDI + d] = acc;
}

// ---------------------------------------------------------------------------
// Selective scan v8: LDS-staged chunks + 4 states/thread in registers.
// Block = 256 threads = 64 channels x 4 state-quads (sq = wave id).
constexpr int kNSEG = 16;
constexpr int kSEGL = kL / kNSEG;     // 64
constexpr int kCT   = 32;             // steps per chunk
constexpr int kP    = kB * kDI * 16;  // 98304 (b,d,s) tuples
constexpr float kLOG2E = 1.44269504089f;

__global__ __launch_bounds__(256, 5) void scan8_kernel(
    const float* __restrict__ u, const float* __restrict__ g,
    const float* __restrict__ dt, const float* __restrict__ xdbl,
    const float* __restrict__ A_log,
    float* __restrict__ PA, float* __restrict__ QA,
    float* __restrict__ accA, float* __restrict__ wcA,
    float* __restrict__ ugA)
{
    __shared__ float uS [kCT][64];     // 8 KB
    __shared__ float gS [kCT][64];     // 8 KB
    __shared__ float dtS[kCT][64];     // 8 KB
    __shared__ float bcS[kCT][34];     // B|C (32 used) + pad   4.25 KB
    const int t = threadIdx.x;
    const int blk = blockIdx.x;          // grid = 96 * kNSEG = 1536
    const int seg = blk & (kNSEG - 1);
    const int bd  = blk >> 4;            // 0..95
    const int b   = bd / 24;
    const int d0  = (bd % 24) * 64;
    const int c   = t & 63;              // channel
    const int sq  = t >> 6;              // state-quad (wave-uniform)
    const int d   = d0 + c;
    const int lb  = seg * kSEGL;

    f32x4 Av;
    {
        float4 al = *(const float4*)&A_log[d * kDS + sq * 4];
        Av.x = -__expf(al.x) * kLOG2E;
        Av.y = -__expf(al.y) * kLOG2E;
        Av.z = -__expf(al.z) * kLOG2E;
        Av.w = -__expf(al.w) * kLOG2E;
    }

    const float* u_base  = u  + ((size_t)b << 10) * kDI + d0;
    const float* g_base  = g  + ((size_t)b << 10) * kDI + d0;
    const float* dt_base = dt + ((size_t)b << 10) * kDI + d0;
    const float* bc_base = xdbl + ((size_t)b << 10) * kNX + kDTR;
    const int rb = t >> 3, cb = (t & 7) * 4;

    float4 ru[2], rg[2], rdt[2], rbc;
    auto load_chunk = [&](int l0) {
        #pragma unroll
        for (int j = 0; j < 2; ++j) {
            int idx = t + 256 * j;
            int row = idx >> 4, col = (idx & 15) * 4;
            ru [j] = *(const float4*)(u_base  + (size_t)(l0 + row) * kDI + col);
            rg [j] = *(const float4*)(g_base  + (size_t)(l0 + row) * kDI + col);
            rdt[j] = *(const float4*)(dt_base + (size_t)(l0 + row) * kDI + col);
        }
        rbc = *(const float4*)(bc_base + (size_t)(l0 + rb) * kNX + cb);
    };
    auto store_chunk = [&]() {
        #pragma unroll
        for (int j = 0; j < 2; ++j) {
            int idx = t + 256 * j;
            int row = idx >> 4, col = (idx & 15) * 4;
            *(float4*)&uS [row][col] = ru [j];
            *(float4*)&gS [row][col] = rg [j];
            *(float4*)&dtS[row][col] = rdt[j];
        }
        *(float4*)&bcS[rb][cb] = rbc;
    };

    f32x4 h   = {0.f, 0.f, 0.f, 0.f};
    f32x4 cp  = {1.f, 1.f, 1.f, 1.f};
    f32x4 acc = {0.f, 0.f, 0.f, 0.f};
    f32x4 wc  = {0.f, 0.f, 0.f, 0.f};
    float ug = 0.f;

    load_chunk(lb);
    store_chunk();
    __syncthreads();

    #pragma unroll
    for (int ck = 0; ck < kSEGL / kCT; ++ck) {
        if (ck + 1 < kSEGL / kCT) load_chunk(lb + (ck + 1) * kCT);
        #pragma unroll 8
        for (int i = 0; i < kCT; ++i) {
            const float dtv = dtS[i][c];
            const float uv  = uS [i][c];
            const float gv  = gS [i][c];
            const f32x4 Bv = *(const f32x4*)&bcS[i][sq * 4];        // uniform
            const f32x4 Cv = *(const f32x4*)&bcS[i][16 + sq * 4];   // uniform
            const f32x4 pm = dtv * Av;
            f32x4 dA;
            dA.x = exp2f(pm.x); dA.y = exp2f(pm.y);
            dA.z = exp2f(pm.z); dA.w = exp2f(pm.w);
            const float dtu = dtv * uv;
            h  = dA * h + dtu * Bv;
            cp = cp * dA;
            const f32x4 cg = Cv * gv;
            acc = h * cg + acc;
            wc  = cp * cg + wc;
            ug  = fmaf(uv, gv, ug);
        }
        if (ck + 1 < kSEGL / kCT) {
            __syncthreads();
            store_chunk();
            __syncthreads();
        }
    }

    const int p = ((b * kDI + d) << 4) + sq * 4;
    const size_t o = (size_t)seg * kP + p;
    *(f32x4*)&PA[o]   = cp;
    *(f32x4*)&QA[o]   = h;
    *(f32x4*)&accA[o] = acc;
    *(f32x4*)&wcA[o]  = wc;
    if (sq == 0) ugA[(size_t)seg * (kB * kDI) + b * kDI + d] = ug;
}

// Pass 2: chain segments, reduce over states, add D*ug, write ysum.
__global__ __launch_bounds__(256) void scan_combine_kernel(
    const float* __restrict__ PA, const float* __restrict__ QA,
    const float* __restrict__ accA, const float* __restrict__ wcA,
    const float* __restrict__ ugA, const float* __restrict__ Dvec,
    float* __restrict__ ysum)
{
    const int p = blockIdx.x * 256 + threadIdx.x;   // 0..kP-1
    const int s = p & 15;
    const int bd = p >> 4;                          // b*kDI + d
    float h = 0.f, tot = 0.f;
    #pragma unroll
    for (int seg = 0; seg < kNSEG; ++seg) {
        const size_t o = (size_t)seg * kP + p;
        tot += accA[o] + h * wcA[o];
        h = fmaf(PA[o], h, QA[o]);
    }
    #pragma unroll
    for (int o2 = 1; o2 < 16; o2 <<= 1) tot += __shfl_xor(tot, o2, 64);
    if (s == 0) {
        float ug = 0.f;
        #pragma unroll
        for (int seg = 0; seg < kNSEG; ++seg)
            ug += ugA[(size_t)seg * (kB * kDI) + bd];
        ysum[bd] = tot + Dvec[bd % kDI] * ug;
    }
}

// ---------------------------------------------------------------------------
// out[b][j] = (1/L) * sum_d ysum[b][d] * Wout[j][d]
__global__ __launch_bounds__(256) void final_kernel(
    const float* __restrict__ ysum, const float* __restrict__ Wout,
    float* __restrict__ out)
{
    int gw = blockIdx.x * 4 + (threadIdx.x >> 6);
    int lane = threadIdx.x & 63;
    int b = gw / kDM;
    int j = gw - b * kDM;
    const float* yrow = ysum + (size_t)b * kDI;
    const float* wrow = Wout + (size_t)j * kDI;
    float acc = 0.f;
    for (int k = lane; k < kDI; k += 64) acc = fmaf(yrow[k], wrow[k], acc);
    #pragma unroll
    for (int o = 32; o; o >>= 1) acc += __shfl_xor(acc, o, 64);
    if (lane == 0) out[gw] = acc * (1.f / (float)kL);
}

// ---------------------------------------------------------------------------
extern "C" void kernel_launch(void* const* d_in, const int* in_sizes, int n_in,
                              void* d_out, int out_size, void* d_ws, size_t ws_size,
                              hipStream_t stream)
{
    const float* image_tokens = (const float*)d_in[0];
    const float* text_tokens  = (const float*)d_in[1];
    const float* W_txt        = (const float*)d_in[2];
    const float* b_txt        = (const float*)d_in[3];
    const float* in_proj_w    = (const float*)d_in[4];
    const float* conv_w       = (const float*)d_in[5];
    const float* conv_b       = (const float*)d_in[6];
    const float* x_proj_w     = (const float*)d_in[7];
    const float* dt_proj_w    = (const float*)d_in[8];
    const float* dt_proj_b    = (const float*)d_in[9];
    const float* A_log        = (const float*)d_in[10];
    const float* Dvec         = (const float*)d_in[11];
    const float* out_proj_w   = (const float*)d_in[12];
    float* out = (float*)d_out;

    // workspace layout (bytes, all 256B-aligned). Region lifetimes:
    //   dtreg: tokb+wb (until in_proj) -> part (xproj) -> dt (dtproj..scan)
    //   xraw:  conv input (until conv) -> PA/QA/accA/wcA partials (scan..combine)
    char* p = (char*)d_ws;
    float* txt  = (float*)p;                      p += 12288;
    float* dtreg = (float*)p;                     p += (size_t)kM * kDI * 4;       // 25.2 MB
    float* xraw = (float*)p;                      p += (size_t)kM * kDI * 4;       // 25.2 MB
    float* gbuf = (float*)p;                      p += (size_t)kM * kDI * 4;       // 25.2 MB
    float* xbuf = (float*)p;                      p += (size_t)kM * kDI * 4;       // 25.2 MB
    float* xdbl = (float*)p;                      p += (size_t)kM * kNX * 4;       // 1.3 MB
    float* ysum = (float*)p;                      p += 32768;
    float* ugA  = (float*)p;                      p += (size_t)kNSEG * kB * kDI * 4; // 0.4 MB

    unsigned short* tokb = (unsigned short*)dtreg;          // 6.3 MB
    unsigned short* wb   = tokb + (size_t)kM * kDM;         // 4.7 MB
    float* part = dtreg;                                    // 10.5 MB (after in_proj)
    float* dtb  = dtreg;                                    // 25.2 MB (after xproj)
    float* PA   = xraw;                                     // partials
    float* QA   = PA + (size_t)kNSEG * kP;
    float* accA = QA + (size_t)kNSEG * kP;
    float* wcA  = accA + (size_t)kNSEG * kP;

    // 1) txt projection
    txt_kernel<<<dim3(kB * kDM / 4), dim3(256), 0, stream>>>(text_tokens, W_txt, b_txt, txt);

    // 2) tokens = bf16(image + txt)
    tokens_bf16_kernel<<<dim3(kM * kDM / 4 / 256), dim3(256), 0, stream>>>(image_tokens, txt, tokb);

    // 3) cast in_proj_w to bf16
    castw_kernel<<<dim3((2 * kDI * kDM / 4 + 255) / 256), dim3(256), 0, stream>>>(
        in_proj_w, wb, 2 * kDI * kDM / 4);

    // 4) in_proj (bf16 MFMA): x half -> xraw, z half -> g = silu(z)
    mfma_inproj_kernel<<<dim3(kM / 128, 2 * kDI / 128), dim3(256), 0, stream>>>(
        tokb, wb, xraw, gbuf);

    // 5) causal conv + silu (float4)
    conv_silu_kernel<<<dim3(kM * kDI / 4 / 256), dim3(256), 0, stream>>>(
        xraw, conv_w, conv_b, xbuf);

    // 6) x_proj split-K (part overlays dtreg; tokb/wb dead now)
    xproj_splitk_kernel<<<dim3(kM / 64, kKS), dim3(256), 0, stream>>>(xbuf, x_proj_w, part);
    xproj_reduce_kernel<<<dim3(kM * kNX / 256), dim3(256), 0, stream>>>(part, xdbl);

    // 7) dt_proj (round-2 proven gemm structure) -> dtb
    dtproj_gemm_kernel<<<dim3(kM / 64, kDI / 64), dim3(256), 0, stream>>>(
        xdbl, dt_proj_w, dt_proj_b, dtb);

    // 8) LDS-staged register-state segmented scan + combine
    scan8_kernel<<<dim3(kB * 24 * kNSEG), dim3(256), 0, stream>>>(
        xbuf, gbuf, dtb, xdbl, A_log, PA, QA, accA, wcA, ugA);
    scan_combine_kernel<<<dim3(kP / 256), dim3(256), 0, stream>>>(
        PA, QA, accA, wcA, ugA, Dvec, ysum);

    // 9) out = (ysum/L) @ out_proj_w.T
    final_kernel<<<dim3(kB * kDM / 4), dim3(256), 0, stream>>>(ysum, out_proj_w, out);
}

// Round 12
// 206.838 us; speedup vs baseline: 1.4585x; 1.0013x over previous
//
#include <hip/hip_runtime.h>
#include <math.h>

// Problem constants
constexpr int kB   = 4;
constexpr int kL   = 1024;
constexpr int kDM  = 768;
constexpr int kDI  = 1536;   // 2*kDM
constexpr int kDS  = 16;     // D_STATE
constexpr int kDTR = 48;     // DT_RANK
constexpr int kNX  = 80;     // DTR + 2*DS
constexpr int kM   = kB * kL; // 4096
constexpr int kLTXT = 128;

typedef __attribute__((ext_vector_type(8))) short bf16x8;
typedef __attribute__((ext_vector_type(4))) float f32x4;

__device__ inline unsigned short f2bf(float f) {
    unsigned u = __float_as_uint(f);
    u = (u + 0x7FFFu + ((u >> 16) & 1u)) >> 16;   // RNE
    return (unsigned short)u;
}

__device__ __forceinline__ void gl2lds16(const unsigned short* g, unsigned short* l) {
    __builtin_amdgcn_global_load_lds(
        (const __attribute__((address_space(1))) unsigned int*)g,
        (__attribute__((address_space(3))) unsigned int*)l, 16, 0, 0);
}

// ---------------------------------------------------------------------------
// txt[b][j] = b_txt[j] + sum_k text_tokens[b,0,k] * W_txt[j,k]
__global__ __launch_bounds__(256) void txt_kernel(
    const float* __restrict__ text, const float* __restrict__ Wt,
    const float* __restrict__ bt, float* __restrict__ txt)
{
    int gw = blockIdx.x * 4 + (threadIdx.x >> 6);
    int lane = threadIdx.x & 63;
    int b = gw / kDM;
    int j = gw - b * kDM;
    const float* trow = text + (size_t)b * kLTXT * kDM;
    const float* wrow = Wt + (size_t)j * kDM;
    float acc = 0.f;
    for (int k = lane; k < kDM; k += 64) acc = fmaf(trow[k], wrow[k], acc);
    #pragma unroll
    for (int o = 32; o; o >>= 1) acc += __shfl_xor(acc, o, 64);
    if (lane == 0) txt[gw] = acc + bt[j];
}

// ---------------------------------------------------------------------------
// tokens_bf16[m][k] = bf16(image[m][k] + txt[m/1024][k])
__global__ __launch_bounds__(256) void tokens_bf16_kernel(
    const float* __restrict__ img, const float* __restrict__ txt,
    unsigned short* __restrict__ tok)
{
    int i = blockIdx.x * 256 + threadIdx.x;        // over kM*kDM/4
    float4 a = ((const float4*)img)[i];
    int m = i / (kDM / 4);
    int k4 = i - m * (kDM / 4);
    float4 tv = ((const float4*)(txt + (size_t)(m >> 10) * kDM))[k4];
    ushort4 o;
    o.x = f2bf(a.x + tv.x); o.y = f2bf(a.y + tv.y);
    o.z = f2bf(a.z + tv.z); o.w = f2bf(a.w + tv.w);
    ((ushort4*)tok)[i] = o;
}

// ---------------------------------------------------------------------------
// cast in_proj_w (f32, [3072][768]) -> bf16
__global__ __launch_bounds__(256) void castw_kernel(
    const float* __restrict__ w, unsigned short* __restrict__ o, int n4)
{
    int i = blockIdx.x * 256 + threadIdx.x;
    if (i >= n4) return;
    float4 a = ((const float4*)w)[i];
    ushort4 v;
    v.x = f2bf(a.x); v.y = f2bf(a.y); v.z = f2bf(a.z); v.w = f2bf(a.w);
    ((ushort4*)o)[i] = v;
}

// ---------------------------------------------------------------------------
// bf16 MFMA GEMM for in_proj (global_load_lds width-16, double-buffered LDS).
// M=4096, N=3072, K=768. BM=BN=128, BK=32, 256 threads (4 waves, 2x2).
// n<1536 -> xout; n>=1536 -> gout = silu(v)
__global__ __launch_bounds__(256) void mfma_inproj_kernel(
    const unsigned short* __restrict__ A, const unsigned short* __restrict__ W,
    float* __restrict__ xout, float* __restrict__ gout)
{
    __shared__ unsigned short Asm[2][128][32];
    __shared__ unsigned short Wsm[2][128][32];
    const int t = threadIdx.x;
    const int lane = t & 63;
    const int wv = t >> 6;             // wave 0..3
    const int wr = wv >> 1, wc = wv & 1;
    const int m0 = blockIdx.x * 128;
    const int n0 = blockIdx.y * 128;

    const int srow = lane >> 2;          // 0..15
    const int scol = (lane & 3) * 8;     // bf16 elem 0,8,16,24
    const unsigned short* agp  = A + (size_t)(m0 + wv * 32 + srow) * kDM + scol;
    const unsigned short* agp2 = agp + 16 * kDM;
    const unsigned short* wgp  = W + (size_t)(n0 + wv * 32 + srow) * kDM + scol;
    const unsigned short* wgp2 = wgp + 16 * kDM;

    auto stage = [&](int buf, int k0) {
        gl2lds16(agp  + k0, &Asm[buf][wv * 32][0]);
        gl2lds16(agp2 + k0, &Asm[buf][wv * 32 + 16][0]);
        gl2lds16(wgp  + k0, &Wsm[buf][wv * 32][0]);
        gl2lds16(wgp2 + k0, &Wsm[buf][wv * 32 + 16][0]);
    };

    f32x4 acc[4][4] = {};
    const int fr = lane & 15;
    const int fk = (lane >> 4) * 8;

    stage(0, 0);
    __syncthreads();

    int buf = 0;
    for (int k0 = 0; k0 < kDM; k0 += 32) {
        if (k0 + 32 < kDM) stage(buf ^ 1, k0 + 32);
        bf16x8 af[4], wf[4];
        #pragma unroll
        for (int i = 0; i < 4; ++i)
            af[i] = *(const bf16x8*)&Asm[buf][wr * 64 + i * 16 + fr][fk];
        #pragma unroll
        for (int j = 0; j < 4; ++j)
            wf[j] = *(const bf16x8*)&Wsm[buf][wc * 64 + j * 16 + fr][fk];
        #pragma unroll
        for (int i = 0; i < 4; ++i)
            #pragma unroll
            for (int j = 0; j < 4; ++j)
                acc[i][j] = __builtin_amdgcn_mfma_f32_16x16x32_bf16(af[i], wf[j], acc[i][j], 0, 0, 0);
        __syncthreads();
        buf ^= 1;
    }

    const int erow = (lane >> 4) * 4;
    const int ecol = lane & 15;
    #pragma unroll
    for (int i = 0; i < 4; ++i) {
        #pragma unroll
        for (int j = 0; j < 4; ++j) {
            const int gn = n0 + wc * 64 + j * 16 + ecol;
            #pragma unroll
            for (int q = 0; q < 4; ++q) {
                const int gm = m0 + wr * 64 + i * 16 + erow + q;
                float v = acc[i][j][q];
                if (gn < kDI) {
                    xout[(size_t)gm * kDI + gn] = v;
                } else {
                    gout[(size_t)gm * kDI + (gn - kDI)] = v / (1.f + __expf(-v));
                }
            }
        }
    }
}

// ---------------------------------------------------------------------------
// x_proj split-K: part[ks][m][n] = sum_{k in seg ks} x[m][k] * W[n][k]
constexpr int kKS   = 8;
constexpr int kKSEG = kDI / kKS;   // 192

__global__ __launch_bounds__(256) void xproj_splitk_kernel(
    const float* __restrict__ A, const float* __restrict__ W,
    float* __restrict__ part)
{
    __shared__ float As[16][68];
    __shared__ float Ws[16][84];
    const int t = threadIdx.x;
    const int m0 = blockIdx.x * 64;
    const int kbase = blockIdx.y * kKSEG;
    const int lrow = t >> 2, lk4 = (t & 3) << 2;
    const int ci = (t & 15) << 2;      // 4 rows
    const int cj = (t >> 4) * 5;       // 5 cols (16*5 = 80)
    float acc[4][5] = {};
    const float* aptr = A + (size_t)(m0 + lrow) * kDI + kbase + lk4;

    for (int k0 = 0; k0 < kKSEG; k0 += 16) {
        float4 av = *(const float4*)(aptr + k0);
        if (k0) __syncthreads();
        As[lk4+0][lrow] = av.x; As[lk4+1][lrow] = av.y;
        As[lk4+2][lrow] = av.z; As[lk4+3][lrow] = av.w;
        #pragma unroll
        for (int i = 0; i < 5; ++i) {
            int idx = t + 256 * i;
            int n = idx % 80;
            int k = idx / 80;
            Ws[k][n] = W[(size_t)n * kDI + kbase + k0 + k];
        }
        __syncthreads();
        #pragma unroll
        for (int k = 0; k < 16; ++k) {
            const float4 a4 = *(const float4*)&As[k][ci];
            const float aa[4] = {a4.x, a4.y, a4.z, a4.w};
            float ww[5];
            #pragma unroll
            for (int j = 0; j < 5; ++j) ww[j] = Ws[k][cj + j];
            #pragma unroll
            for (int i = 0; i < 4; ++i)
                #pragma unroll
                for (int j = 0; j < 5; ++j)
                    acc[i][j] = fmaf(aa[i], ww[j], acc[i][j]);
        }
    }

    float* pbase = part + ((size_t)blockIdx.y * kM) * kNX;
    #pragma unroll
    for (int i = 0; i < 4; ++i)
        #pragma unroll
        for (int j = 0; j < 5; ++j)
            pbase[(size_t)(m0 + ci + i) * kNX + cj + j] = acc[i][j];
}

__global__ __launch_bounds__(256) void xproj_reduce_kernel(
    const float* __restrict__ part, float* __restrict__ xdbl)
{
    int i = blockIdx.x * 256 + threadIdx.x;    // over kM*kNX
    float s = 0.f;
    #pragma unroll
    for (int k = 0; k < kKS; ++k) s += part[(size_t)k * kM * kNX + i];
    xdbl[i] = s;
}

// ---------------------------------------------------------------------------
// dt_proj v4 = round-2 proven gemm structure (VGPR ~36, no spill).
// dt[m][n] = softplus(sum_k xdbl[m][k]*Wd[n][k] + b[n]); K=48, BK=16.
__global__ __launch_bounds__(256) void dtproj_gemm_kernel(
    const float* __restrict__ A, const float* __restrict__ W,
    const float* __restrict__ bias, float* __restrict__ dt)
{
    __shared__ float As[16][68];
    __shared__ float Ws[16][68];
    const int t = threadIdx.x;
    const int m0 = blockIdx.x * 64;
    const int n0 = blockIdx.y * 64;
    const int lrow = t >> 2;          // 0..63
    const int lk4  = (t & 3) << 2;    // 0,4,8,12
    const int ci   = (t & 15) << 2;
    const int cj   = (t >> 4) << 2;
    float acc[4][4] = {};
    const float* aptr = A + (size_t)(m0 + lrow) * kNX + lk4;
    const float* wptr = W + (size_t)(n0 + lrow) * kDTR + lk4;

    for (int k0 = 0; k0 < kDTR; k0 += 16) {
        float4 av = *(const float4*)(aptr + k0);
        float4 wv = *(const float4*)(wptr + k0);
        if (k0) __syncthreads();
        As[lk4+0][lrow] = av.x; As[lk4+1][lrow] = av.y;
        As[lk4+2][lrow] = av.z; As[lk4+3][lrow] = av.w;
        Ws[lk4+0][lrow] = wv.x; Ws[lk4+1][lrow] = wv.y;
        Ws[lk4+2][lrow] = wv.z; Ws[lk4+3][lrow] = wv.w;
        __syncthreads();
        #pragma unroll
        for (int k = 0; k < 16; ++k) {
            const float4 a4 = *(const float4*)&As[k][ci];
            const float4 w4 = *(const float4*)&Ws[k][cj];
            const float aa[4] = {a4.x, a4.y, a4.z, a4.w};
            const float ww[4] = {w4.x, w4.y, w4.z, w4.w};
            #pragma unroll
            for (int i = 0; i < 4; ++i)
                #pragma unroll
                for (int j = 0; j < 4; ++j)
                    acc[i][j] = fmaf(aa[i], ww[j], acc[i][j]);
        }
    }

    #pragma unroll
    for (int i = 0; i < 4; ++i) {
        const int gm = m0 + ci + i;
        #pragma unroll
        for (int j = 0; j < 4; ++j) {
            const int gn = n0 + cj + j;
            float v = acc[i][j] + bias[gn];
            v = (v > 20.f) ? v : log1pf(__expf(v));   // softplus
            dt[(size_t)gm * kDI + gn] = v;
        }
    }
}

// ---------------------------------------------------------------------------
// causal depthwise conv (k=4) + SiLU, float4 over d
__global__ __launch_bounds__(256) void conv_silu_kernel(
    const float* __restrict__ xraw, const float* __restrict__ cw,
    const float* __restrict__ cb, float* __restrict__ xout)
{
    int i = blockIdx.x * 256 + threadIdx.x;     // over kM*kDI/4
    int d4 = i % (kDI / 4);
    int ml = i / (kDI / 4);
    int l = ml & (kL - 1);
    const int d = d4 * 4;
    float4 acc = *(const float4*)&cb[d];
    const float* base = xraw + (size_t)ml * kDI + d - 3 * (size_t)kDI;
    float4 w0 = *(const float4*)&cw[(d + 0) * 4];
    float4 w1 = *(const float4*)&cw[(d + 1) * 4];
    float4 w2 = *(const float4*)&cw[(d + 2) * 4];
    float4 w3 = *(const float4*)&cw[(d + 3) * 4];
    const float wj[4][4] = {{w0.x, w1.x, w2.x, w3.x}, {w0.y, w1.y, w2.y, w3.y},
                            {w0.z, w1.z, w2.z, w3.z}, {w0.w, w1.w, w2.w, w3.w}};
    #pragma unroll
    for (int j = 0; j < 4; ++j) {
        if (l - 3 + j >= 0) {
            float4 xv = *(const float4*)(base + (size_t)j * kDI);
            acc.x = fmaf(xv.x, wj[j][0], acc.x);
            acc.y = fmaf(xv.y, wj[j][1], acc.y);
            acc.z = fmaf(xv.z, wj[j][2], acc.z);
            acc.w = fmaf(xv.w, wj[j][3], acc.w);
        }
    }
    acc.x /= (1.f + __expf(-acc.x));
    acc.y /= (1.f + __expf(-acc.y));
    acc.z /= (1.f + __expf(-acc.z));
    acc.w /= (1.f + __expf(-acc.w));
    *(float4*)&xout[(size_t)ml * kDI + d] = acc;
}

// ---------------------------------------------------------------------------
// Selective scan v9: scan8 + COALESCED partial layout.
// Partials stored as [seg][sq][b*kDI+d][4]: lane c writes 16B at 16B stride
// -> 1KB/wave coalesced (v8's [bd][s] layout had 64B lane stride = 6x
// write amplification, 153MB vs 26MB logical).
constexpr int kNSEG = 16;
constexpr int kSEGL = kL / kNSEG;     // 64
constexpr int kCT   = 32;             // steps per chunk
constexpr int kBD   = kB * kDI;       // 6144
constexpr int kP    = kBD * 16;       // 98304 (b,d,s) tuples
constexpr float kLOG2E = 1.44269504089f;

__global__ __launch_bounds__(256, 5) void scan9_kernel(
    const float* __restrict__ u, const float* __restrict__ g,
    const float* __restrict__ dt, const float* __restrict__ xdbl,
    const float* __restrict__ A_log,
    float* __restrict__ PA, float* __restrict__ QA,
    float* __restrict__ accA, float* __restrict__ wcA,
    float* __restrict__ ugA)
{
    __shared__ float uS [kCT][64];     // 8 KB
    __shared__ float gS [kCT][64];     // 8 KB
    __shared__ float dtS[kCT][64];     // 8 KB
    __shared__ float bcS[kCT][34];     // B|C (32 used) + pad   4.25 KB
    const int t = threadIdx.x;
    const int blk = blockIdx.x;          // grid = 96 * kNSEG = 1536
    const int seg = blk & (kNSEG - 1);
    const int bd  = blk >> 4;            // 0..95
    const int b   = bd / 24;
    const int d0  = (bd % 24) * 64;
    const int c   = t & 63;              // channel
    const int sq  = t >> 6;              // state-quad (wave-uniform)
    const int d   = d0 + c;
    const int lb  = seg * kSEGL;

    f32x4 Av;
    {
        float4 al = *(const float4*)&A_log[d * kDS + sq * 4];
        Av.x = -__expf(al.x) * kLOG2E;
        Av.y = -__expf(al.y) * kLOG2E;
        Av.z = -__expf(al.z) * kLOG2E;
        Av.w = -__expf(al.w) * kLOG2E;
    }

    const float* u_base  = u  + ((size_t)b << 10) * kDI + d0;
    const float* g_base  = g  + ((size_t)b << 10) * kDI + d0;
    const float* dt_base = dt + ((size_t)b << 10) * kDI + d0;
    const float* bc_base = xdbl + ((size_t)b << 10) * kNX + kDTR;
    const int rb = t >> 3, cb = (t & 7) * 4;

    float4 ru[2], rg[2], rdt[2], rbc;
    auto load_chunk = [&](int l0) {
        #pragma unroll
        for (int j = 0; j < 2; ++j) {
            int idx = t + 256 * j;
            int row = idx >> 4, col = (idx & 15) * 4;
            ru [j] = *(const float4*)(u_base  + (size_t)(l0 + row) * kDI + col);
            rg [j] = *(const float4*)(g_base  + (size_t)(l0 + row) * kDI + col);
            rdt[j] = *(const float4*)(dt_base + (size_t)(l0 + row) * kDI + col);
        }
        rbc = *(const float4*)(bc_base + (size_t)(l0 + rb) * kNX + cb);
    };
    auto store_chunk = [&]() {
        #pragma unroll
        for (int j = 0; j < 2; ++j) {
            int idx = t + 256 * j;
            int row = idx >> 4, col = (idx & 15) * 4;
            *(float4*)&uS [row][col] = ru [j];
            *(float4*)&gS [row][col] = rg [j];
            *(float4*)&dtS[row][col] = rdt[j];
        }
        *(float4*)&bcS[rb][cb] = rbc;
    };

    f32x4 h   = {0.f, 0.f, 0.f, 0.f};
    f32x4 cp  = {1.f, 1.f, 1.f, 1.f};
    f32x4 acc = {0.f, 0.f, 0.f, 0.f};
    f32x4 wc  = {0.f, 0.f, 0.f, 0.f};
    float ug = 0.f;

    load_chunk(lb);
    store_chunk();
    __syncthreads();

    #pragma unroll
    for (int ck = 0; ck < kSEGL / kCT; ++ck) {
        if (ck + 1 < kSEGL / kCT) load_chunk(lb + (ck + 1) * kCT);
        #pragma unroll 8
        for (int i = 0; i < kCT; ++i) {
            const float dtv = dtS[i][c];
            const float uv  = uS [i][c];
            const float gv  = gS [i][c];
            const f32x4 Bv = *(const f32x4*)&bcS[i][sq * 4];        // uniform
            const f32x4 Cv = *(const f32x4*)&bcS[i][16 + sq * 4];   // uniform
            const f32x4 pm = dtv * Av;
            f32x4 dA;
            dA.x = exp2f(pm.x); dA.y = exp2f(pm.y);
            dA.z = exp2f(pm.z); dA.w = exp2f(pm.w);
            const float dtu = dtv * uv;
            h  = dA * h + dtu * Bv;
            cp = cp * dA;
            const f32x4 cg = Cv * gv;
            acc = h * cg + acc;
            wc  = cp * cg + wc;
            ug  = fmaf(uv, gv, ug);
        }
        if (ck + 1 < kSEGL / kCT) {
            __syncthreads();
            store_chunk();
            __syncthreads();
        }
    }

    // coalesced: [seg][sq][b*kDI+d][4] — lane stride 16B
    const size_t o = (size_t)seg * kP + ((size_t)sq * kBD + b * kDI + d) * 4;
    *(f32x4*)&PA[o]   = cp;
    *(f32x4*)&QA[o]   = h;
    *(f32x4*)&accA[o] = acc;
    *(f32x4*)&wcA[o]  = wc;
    if (sq == 0) ugA[(size_t)seg * kBD + b * kDI + d] = ug;
}

// Pass 2: chain segments (transposed layout), reduce states, add D*ug.
__global__ __launch_bounds__(256) void scan_combine_kernel(
    const float* __restrict__ PA, const float* __restrict__ QA,
    const float* __restrict__ accA, const float* __restrict__ wcA,
    const float* __restrict__ ugA, const float* __restrict__ Dvec,
    float* __restrict__ ysum)
{
    const int p = blockIdx.x * 256 + threadIdx.x;   // 0..kP-1
    const int s = p & 15;
    const int bd = p >> 4;                          // b*kDI + d
    const size_t pbase = ((size_t)(s >> 2) * kBD + bd) * 4 + (s & 3);
    float h = 0.f, tot = 0.f;
    #pragma unroll
    for (int seg = 0; seg < kNSEG; ++seg) {
        const size_t o = (size_t)seg * kP + pbase;
        tot += accA[o] + h * wcA[o];
        h = fmaf(PA[o], h, QA[o]);
    }
    #pragma unroll
    for (int o2 = 1; o2 < 16; o2 <<= 1) tot += __shfl_xor(tot, o2, 64);
    if (s == 0) {
        float ug = 0.f;
        #pragma unroll
        for (int seg = 0; seg < kNSEG; ++seg)
            ug += ugA[(size_t)seg * kBD + bd];
        ysum[bd] = tot + Dvec[bd % kDI] * ug;
    }
}

// ---------------------------------------------------------------------------
// out[b][j] = (1/L) * sum_d ysum[b][d] * Wout[j][d]
__global__ __launch_bounds__(256) void final_kernel(
    const float* __restrict__ ysum, const float* __restrict__ Wout,
    float* __restrict__ out)
{
    int gw = blockIdx.x * 4 + (threadIdx.x >> 6);
    int lane = threadIdx.x & 63;
    int b = gw / kDM;
    int j = gw - b * kDM;
    const float* yrow = ysum + (size_t)b * kDI;
    const float* wrow = Wout + (size_t)j * kDI;
    float acc = 0.f;
    for (int k = lane; k < kDI; k += 64) acc = fmaf(yrow[k], wrow[k], acc);
    #pragma unroll
    for (int o = 32; o; o >>= 1) acc += __shfl_xor(acc, o, 64);
    if (lane == 0) out[gw] = acc * (1.f / (float)kL);
}

// ---------------------------------------------------------------------------
extern "C" void kernel_launch(void* const* d_in, const int* in_sizes, int n_in,
                              void* d_out, int out_size, void* d_ws, size_t ws_size,
                              hipStream_t stream)
{
    const float* image_tokens = (const float*)d_in[0];
    const float* text_tokens  = (const float*)d_in[1];
    const float* W_txt        = (const float*)d_in[2];
    const float* b_txt        = (const float*)d_in[3];
    const float* in_proj_w    = (const float*)d_in[4];
    const float* conv_w       = (const float*)d_in[5];
    const float* conv_b       = (const float*)d_in[6];
    const float* x_proj_w     = (const float*)d_in[7];
    const float* dt_proj_w    = (const float*)d_in[8];
    const float* dt_proj_b    = (const float*)d_in[9];
    const float* A_log        = (const float*)d_in[10];
    const float* Dvec         = (const float*)d_in[11];
    const float* out_proj_w   = (const float*)d_in[12];
    float* out = (float*)d_out;

    // workspace layout (bytes, all 256B-aligned). Region lifetimes:
    //   dtreg: tokb+wb (until in_proj) -> part (xproj) -> dt (dtproj..scan)
    //   xraw:  conv input (until conv) -> PA/QA/accA/wcA partials (scan..combine)
    char* p = (char*)d_ws;
    float* txt  = (float*)p;                      p += 12288;
    float* dtreg = (float*)p;                     p += (size_t)kM * kDI * 4;       // 25.2 MB
    float* xraw = (float*)p;                      p += (size_t)kM * kDI * 4;       // 25.2 MB
    float* gbuf = (float*)p;                      p += (size_t)kM * kDI * 4;       // 25.2 MB
    float* xbuf = (float*)p;                      p += (size_t)kM * kDI * 4;       // 25.2 MB
    float* xdbl = (float*)p;                      p += (size_t)kM * kNX * 4;       // 1.3 MB
    float* ysum = (float*)p;                      p += 32768;
    float* ugA  = (float*)p;                      p += (size_t)kNSEG * kBD * 4;    // 0.4 MB

    unsigned short* tokb = (unsigned short*)dtreg;          // 6.3 MB
    unsigned short* wb   = tokb + (size_t)kM * kDM;         // 4.7 MB
    float* part = dtreg;                                    // 10.5 MB (after in_proj)
    float* dtb  = dtreg;                                    // 25.2 MB (after xproj)
    float* PA   = xraw;                                     // partials
    float* QA   = PA + (size_t)kNSEG * kP;
    float* accA = QA + (size_t)kNSEG * kP;
    float* wcA  = accA + (size_t)kNSEG * kP;

    // 1) txt projection
    txt_kernel<<<dim3(kB * kDM / 4), dim3(256), 0, stream>>>(text_tokens, W_txt, b_txt, txt);

    // 2) tokens = bf16(image + txt)
    tokens_bf16_kernel<<<dim3(kM * kDM / 4 / 256), dim3(256), 0, stream>>>(image_tokens, txt, tokb);

    // 3) cast in_proj_w to bf16
    castw_kernel<<<dim3((2 * kDI * kDM / 4 + 255) / 256), dim3(256), 0, stream>>>(
        in_proj_w, wb, 2 * kDI * kDM / 4);

    // 4) in_proj (bf16 MFMA): x half -> xraw, z half -> g = silu(z)
    mfma_inproj_kernel<<<dim3(kM / 128, 2 * kDI / 128), dim3(256), 0, stream>>>(
        tokb, wb, xraw, gbuf);

    // 5) causal conv + silu (float4)
    conv_silu_kernel<<<dim3(kM * kDI / 4 / 256), dim3(256), 0, stream>>>(
        xraw, conv_w, conv_b, xbuf);

    // 6) x_proj split-K (part overlays dtreg; tokb/wb dead now)
    xproj_splitk_kernel<<<dim3(kM / 64, kKS), dim3(256), 0, stream>>>(xbuf, x_proj_w, part);
    xproj_reduce_kernel<<<dim3(kM * kNX / 256), dim3(256), 0, stream>>>(part, xdbl);

    // 7) dt_proj (round-2 proven gemm structure) -> dtb
    dtproj_gemm_kernel<<<dim3(kM / 64, kDI / 64), dim3(256), 0, stream>>>(
        xdbl, dt_proj_w, dt_proj_b, dtb);

    // 8) LDS-staged register-state segmented scan (coalesced partials) + combine
    scan9_kernel<<<dim3(kB * 24 * kNSEG), dim3(256), 0, stream>>>(
        xbuf, gbuf, dtb, xdbl, A_log, PA, QA, accA, wcA, ugA);
    scan_combine_kernel<<<dim3(kP / 256), dim3(256), 0, stream>>>(
        PA, QA, accA, wcA, ugA, Dvec, ysum);

    // 9) out = (ysum/L) @ out_proj_w.T
    final_kernel<<<dim3(kB * kDM / 4), dim3(256), 0, stream>>>(ysum, out_proj_w, out);
}

// Round 13
// 188.294 us; speedup vs baseline: 1.6022x; 1.0985x over previous
//
#include <hip/hip_runtime.h>
#include <math.h>

// Problem constants
constexpr int kB   = 4;
constexpr int kL   = 1024;
constexpr int kDM  = 768;
constexpr int kDI  = 1536;   // 2*kDM
constexpr int kDS  = 16;     // D_STATE
constexpr int kDTR = 48;     // DT_RANK
constexpr int kNX  = 80;     // DTR + 2*DS
constexpr int kM   = kB * kL; // 4096
constexpr int kLTXT = 128;

typedef __attribute__((ext_vector_type(8))) short bf16x8;
typedef __attribute__((ext_vector_type(4))) float f32x4;

__device__ inline unsigned short f2bf(float f) {
    unsigned u = __float_as_uint(f);
    u = (u + 0x7FFFu + ((u >> 16) & 1u)) >> 16;   // RNE
    return (unsigned short)u;
}

__device__ __forceinline__ void gl2lds16(const unsigned short* g, unsigned short* l) {
    __builtin_amdgcn_global_load_lds(
        (const __attribute__((address_space(1))) unsigned int*)g,
        (__attribute__((address_space(3))) unsigned int*)l, 16, 0, 0);
}

// ---------------------------------------------------------------------------
// txt[b][j] = b_txt[j] + sum_k text_tokens[b,0,k] * W_txt[j,k]
__global__ __launch_bounds__(256) void txt_kernel(
    const float* __restrict__ text, const float* __restrict__ Wt,
    const float* __restrict__ bt, float* __restrict__ txt)
{
    int gw = blockIdx.x * 4 + (threadIdx.x >> 6);
    int lane = threadIdx.x & 63;
    int b = gw / kDM;
    int j = gw - b * kDM;
    const float* trow = text + (size_t)b * kLTXT * kDM;
    const float* wrow = Wt + (size_t)j * kDM;
    float acc = 0.f;
    for (int k = lane; k < kDM; k += 64) acc = fmaf(trow[k], wrow[k], acc);
    #pragma unroll
    for (int o = 32; o; o >>= 1) acc += __shfl_xor(acc, o, 64);
    if (lane == 0) txt[gw] = acc + bt[j];
}

// ---------------------------------------------------------------------------
// tokens_bf16[m][k] = bf16(image[m][k] + txt[m/1024][k])
__global__ __launch_bounds__(256) void tokens_bf16_kernel(
    const float* __restrict__ img, const float* __restrict__ txt,
    unsigned short* __restrict__ tok)
{
    int i = blockIdx.x * 256 + threadIdx.x;        // over kM*kDM/4
    float4 a = ((const float4*)img)[i];
    int m = i / (kDM / 4);
    int k4 = i - m * (kDM / 4);
    float4 tv = ((const float4*)(txt + (size_t)(m >> 10) * kDM))[k4];
    ushort4 o;
    o.x = f2bf(a.x + tv.x); o.y = f2bf(a.y + tv.y);
    o.z = f2bf(a.z + tv.z); o.w = f2bf(a.w + tv.w);
    ((ushort4*)tok)[i] = o;
}

// ---------------------------------------------------------------------------
// cast in_proj_w (f32, [3072][768]) -> bf16
__global__ __launch_bounds__(256) void castw_kernel(
    const float* __restrict__ w, unsigned short* __restrict__ o, int n4)
{
    int i = blockIdx.x * 256 + threadIdx.x;
    if (i >= n4) return;
    float4 a = ((const float4*)w)[i];
    ushort4 v;
    v.x = f2bf(a.x); v.y = f2bf(a.y); v.z = f2bf(a.z); v.w = f2bf(a.w);
    ((ushort4*)o)[i] = v;
}

// ---------------------------------------------------------------------------
// bf16 MFMA GEMM for in_proj (global_load_lds width-16, double-buffered LDS).
// M=4096, N=3072, K=768. BM=BN=128, BK=32, 256 threads (4 waves, 2x2).
// n<1536 -> xout; n>=1536 -> gout = silu(v)
__global__ __launch_bounds__(256) void mfma_inproj_kernel(
    const unsigned short* __restrict__ A, const unsigned short* __restrict__ W,
    float* __restrict__ xout, float* __restrict__ gout)
{
    __shared__ unsigned short Asm[2][128][32];
    __shared__ unsigned short Wsm[2][128][32];
    const int t = threadIdx.x;
    const int lane = t & 63;
    const int wv = t >> 6;             // wave 0..3
    const int wr = wv >> 1, wc = wv & 1;
    const int m0 = blockIdx.x * 128;
    const int n0 = blockIdx.y * 128;

    const int srow = lane >> 2;          // 0..15
    const int scol = (lane & 3) * 8;     // bf16 elem 0,8,16,24
    const unsigned short* agp  = A + (size_t)(m0 + wv * 32 + srow) * kDM + scol;
    const unsigned short* agp2 = agp + 16 * kDM;
    const unsigned short* wgp  = W + (size_t)(n0 + wv * 32 + srow) * kDM + scol;
    const unsigned short* wgp2 = wgp + 16 * kDM;

    auto stage = [&](int buf, int k0) {
        gl2lds16(agp  + k0, &Asm[buf][wv * 32][0]);
        gl2lds16(agp2 + k0, &Asm[buf][wv * 32 + 16][0]);
        gl2lds16(wgp  + k0, &Wsm[buf][wv * 32][0]);
        gl2lds16(wgp2 + k0, &Wsm[buf][wv * 32 + 16][0]);
    };

    f32x4 acc[4][4] = {};
    const int fr = lane & 15;
    const int fk = (lane >> 4) * 8;

    stage(0, 0);
    __syncthreads();

    int buf = 0;
    for (int k0 = 0; k0 < kDM; k0 += 32) {
        if (k0 + 32 < kDM) stage(buf ^ 1, k0 + 32);
        bf16x8 af[4], wf[4];
        #pragma unroll
        for (int i = 0; i < 4; ++i)
            af[i] = *(const bf16x8*)&Asm[buf][wr * 64 + i * 16 + fr][fk];
        #pragma unroll
        for (int j = 0; j < 4; ++j)
            wf[j] = *(const bf16x8*)&Wsm[buf][wc * 64 + j * 16 + fr][fk];
        #pragma unroll
        for (int i = 0; i < 4; ++i)
            #pragma unroll
            for (int j = 0; j < 4; ++j)
                acc[i][j] = __builtin_amdgcn_mfma_f32_16x16x32_bf16(af[i], wf[j], acc[i][j], 0, 0, 0);
        __syncthreads();
        buf ^= 1;
    }

    const int erow = (lane >> 4) * 4;
    const int ecol = lane & 15;
    #pragma unroll
    for (int i = 0; i < 4; ++i) {
        #pragma unroll
        for (int j = 0; j < 4; ++j) {
            const int gn = n0 + wc * 64 + j * 16 + ecol;
            #pragma unroll
            for (int q = 0; q < 4; ++q) {
                const int gm = m0 + wr * 64 + i * 16 + erow + q;
                float v = acc[i][j][q];
                if (gn < kDI) {
                    xout[(size_t)gm * kDI + gn] = v;
                } else {
                    gout[(size_t)gm * kDI + (gn - kDI)] = v / (1.f + __expf(-v));
                }
            }
        }
    }
}

// ---------------------------------------------------------------------------
// x_proj split-K: part[ks][m][n] = sum_{k in seg ks} x[m][k] * W[n][k]
constexpr int kKS   = 8;
constexpr int kKSEG = kDI / kKS;   // 192

__global__ __launch_bounds__(256) void xproj_splitk_kernel(
    const float* __restrict__ A, const float* __restrict__ W,
    float* __restrict__ part)
{
    __shared__ float As[16][68];
    __shared__ float Ws[16][84];
    const int t = threadIdx.x;
    const int m0 = blockIdx.x * 64;
    const int kbase = blockIdx.y * kKSEG;
    const int lrow = t >> 2, lk4 = (t & 3) << 2;
    const int ci = (t & 15) << 2;      // 4 rows
    const int cj = (t >> 4) * 5;       // 5 cols (16*5 = 80)
    float acc[4][5] = {};
    const float* aptr = A + (size_t)(m0 + lrow) * kDI + kbase + lk4;

    for (int k0 = 0; k0 < kKSEG; k0 += 16) {
        float4 av = *(const float4*)(aptr + k0);
        if (k0) __syncthreads();
        As[lk4+0][lrow] = av.x; As[lk4+1][lrow] = av.y;
        As[lk4+2][lrow] = av.z; As[lk4+3][lrow] = av.w;
        #pragma unroll
        for (int i = 0; i < 5; ++i) {
            int idx = t + 256 * i;
            int n = idx % 80;
            int k = idx / 80;
            Ws[k][n] = W[(size_t)n * kDI + kbase + k0 + k];
        }
        __syncthreads();
        #pragma unroll
        for (int k = 0; k < 16; ++k) {
            const float4 a4 = *(const float4*)&As[k][ci];
            const float aa[4] = {a4.x, a4.y, a4.z, a4.w};
            float ww[5];
            #pragma unroll
            for (int j = 0; j < 5; ++j) ww[j] = Ws[k][cj + j];
            #pragma unroll
            for (int i = 0; i < 4; ++i)
                #pragma unroll
                for (int j = 0; j < 5; ++j)
                    acc[i][j] = fmaf(aa[i], ww[j], acc[i][j]);
        }
    }

    float* pbase = part + ((size_t)blockIdx.y * kM) * kNX;
    #pragma unroll
    for (int i = 0; i < 4; ++i)
        #pragma unroll
        for (int j = 0; j < 5; ++j)
            pbase[(size_t)(m0 + ci + i) * kNX + cj + j] = acc[i][j];
}

__global__ __launch_bounds__(256) void xproj_reduce_kernel(
    const float* __restrict__ part, float* __restrict__ xdbl)
{
    int i = blockIdx.x * 256 + threadIdx.x;    // over kM*kNX
    float s = 0.f;
    #pragma unroll
    for (int k = 0; k < kKS; ++k) s += part[(size_t)k * kM * kNX + i];
    xdbl[i] = s;
}

// ---------------------------------------------------------------------------
// dt_proj v4 = round-2 proven gemm structure (VGPR ~36, no spill).
// dt[m][n] = softplus(sum_k xdbl[m][k]*Wd[n][k] + b[n]); K=48, BK=16.
__global__ __launch_bounds__(256) void dtproj_gemm_kernel(
    const float* __restrict__ A, const float* __restrict__ W,
    const float* __restrict__ bias, float* __restrict__ dt)
{
    __shared__ float As[16][68];
    __shared__ float Ws[16][68];
    const int t = threadIdx.x;
    const int m0 = blockIdx.x * 64;
    const int n0 = blockIdx.y * 64;
    const int lrow = t >> 2;          // 0..63
    const int lk4  = (t & 3) << 2;    // 0,4,8,12
    const int ci   = (t & 15) << 2;
    const int cj   = (t >> 4) << 2;
    float acc[4][4] = {};
    const float* aptr = A + (size_t)(m0 + lrow) * kNX + lk4;
    const float* wptr = W + (size_t)(n0 + lrow) * kDTR + lk4;

    for (int k0 = 0; k0 < kDTR; k0 += 16) {
        float4 av = *(const float4*)(aptr + k0);
        float4 wv = *(const float4*)(wptr + k0);
        if (k0) __syncthreads();
        As[lk4+0][lrow] = av.x; As[lk4+1][lrow] = av.y;
        As[lk4+2][lrow] = av.z; As[lk4+3][lrow] = av.w;
        Ws[lk4+0][lrow] = wv.x; Ws[lk4+1][lrow] = wv.y;
        Ws[lk4+2][lrow] = wv.z; Ws[lk4+3][lrow] = wv.w;
        __syncthreads();
        #pragma unroll
        for (int k = 0; k < 16; ++k) {
            const float4 a4 = *(const float4*)&As[k][ci];
            const float4 w4 = *(const float4*)&Ws[k][cj];
            const float aa[4] = {a4.x, a4.y, a4.z, a4.w};
            const float ww[4] = {w4.x, w4.y, w4.z, w4.w};
            #pragma unroll
            for (int i = 0; i < 4; ++i)
                #pragma unroll
                for (int j = 0; j < 4; ++j)
                    acc[i][j] = fmaf(aa[i], ww[j], acc[i][j]);
        }
    }

    #pragma unroll
    for (int i = 0; i < 4; ++i) {
        const int gm = m0 + ci + i;
        #pragma unroll
        for (int j = 0; j < 4; ++j) {
            const int gn = n0 + cj + j;
            float v = acc[i][j] + bias[gn];
            v = (v > 20.f) ? v : log1pf(__expf(v));   // softplus
            dt[(size_t)gm * kDI + gn] = v;
        }
    }
}

// ---------------------------------------------------------------------------
// causal depthwise conv (k=4) + SiLU, float4 over d
__global__ __launch_bounds__(256) void conv_silu_kernel(
    const float* __restrict__ xraw, const float* __restrict__ cw,
    const float* __restrict__ cb, float* __restrict__ xout)
{
    int i = blockIdx.x * 256 + threadIdx.x;     // over kM*kDI/4
    int d4 = i % (kDI / 4);
    int ml = i / (kDI / 4);
    int l = ml & (kL - 1);
    const int d = d4 * 4;
    float4 acc = *(const float4*)&cb[d];
    const float* base = xraw + (size_t)ml * kDI + d - 3 * (size_t)kDI;
    float4 w0 = *(const float4*)&cw[(d + 0) * 4];
    float4 w1 = *(const float4*)&cw[(d + 1) * 4];
    float4 w2 = *(const float4*)&cw[(d + 2) * 4];
    float4 w3 = *(const float4*)&cw[(d + 3) * 4];
    const float wj[4][4] = {{w0.x, w1.x, w2.x, w3.x}, {w0.y, w1.y, w2.y, w3.y},
                            {w0.z, w1.z, w2.z, w3.z}, {w0.w, w1.w, w2.w, w3.w}};
    #pragma unroll
    for (int j = 0; j < 4; ++j) {
        if (l - 3 + j >= 0) {
            float4 xv = *(const float4*)(base + (size_t)j * kDI);
            acc.x = fmaf(xv.x, wj[j][0], acc.x);
            acc.y = fmaf(xv.y, wj[j][1], acc.y);
            acc.z = fmaf(xv.z, wj[j][2], acc.z);
            acc.w = fmaf(xv.w, wj[j][3], acc.w);
        }
    }
    acc.x /= (1.f + __expf(-acc.x));
    acc.y /= (1.f + __expf(-acc.y));
    acc.z /= (1.f + __expf(-acc.z));
    acc.w /= (1.f + __expf(-acc.w));
    *(float4*)&xout[(size_t)ml * kDI + d] = acc;
}

// ---------------------------------------------------------------------------
// Selective scan v10: scan9 with kCT=16 (LDS 14.1KB) so ALL 1536 blocks
// (6/CU) are resident in ONE round — kills the 1-block/CU tail round that
// was half of scan9's wall time (occupancy 37% = avg of 62.5% + 12.5%).
constexpr int kNSEG = 16;
constexpr int kSEGL = kL / kNSEG;     // 64
constexpr int kCT   = 16;             // steps per chunk
constexpr int kBD   = kB * kDI;       // 6144
constexpr int kP    = kBD * 16;       // 98304 (b,d,s) tuples
constexpr float kLOG2E = 1.44269504089f;

__global__ __launch_bounds__(256, 6) void scan10_kernel(
    const float* __restrict__ u, const float* __restrict__ g,
    const float* __restrict__ dt, const float* __restrict__ xdbl,
    const float* __restrict__ A_log,
    float* __restrict__ PA, float* __restrict__ QA,
    float* __restrict__ accA, float* __restrict__ wcA,
    float* __restrict__ ugA)
{
    __shared__ float uS [kCT][64];     // 4 KB
    __shared__ float gS [kCT][64];     // 4 KB
    __shared__ float dtS[kCT][64];     // 4 KB
    __shared__ float bcS[kCT][34];     // B|C (32 used) + pad   2.1 KB
    const int t = threadIdx.x;
    const int blk = blockIdx.x;          // grid = 96 * kNSEG = 1536
    const int seg = blk & (kNSEG - 1);
    const int bd  = blk >> 4;            // 0..95
    const int b   = bd / 24;
    const int d0  = (bd % 24) * 64;
    const int c   = t & 63;              // channel
    const int sq  = t >> 6;              // state-quad (wave-uniform)
    const int d   = d0 + c;
    const int lb  = seg * kSEGL;

    f32x4 Av;
    {
        float4 al = *(const float4*)&A_log[d * kDS + sq * 4];
        Av.x = -__expf(al.x) * kLOG2E;
        Av.y = -__expf(al.y) * kLOG2E;
        Av.z = -__expf(al.z) * kLOG2E;
        Av.w = -__expf(al.w) * kLOG2E;
    }

    const float* u_base  = u  + ((size_t)b << 10) * kDI + d0;
    const float* g_base  = g  + ((size_t)b << 10) * kDI + d0;
    const float* dt_base = dt + ((size_t)b << 10) * kDI + d0;
    const float* bc_base = xdbl + ((size_t)b << 10) * kNX + kDTR;
    const int sr = t >> 4, scn = (t & 15) * 4;   // u/g/dt: [16][64], 1 f4/thread
    const int rb = (t & 127) >> 3, cbo = (t & 7) * 4;  // bc: [16][32], t<128

    float4 ru, rg, rdt, rbc;
    auto load_chunk = [&](int l0) {
        ru  = *(const float4*)(u_base  + (size_t)(l0 + sr) * kDI + scn);
        rg  = *(const float4*)(g_base  + (size_t)(l0 + sr) * kDI + scn);
        rdt = *(const float4*)(dt_base + (size_t)(l0 + sr) * kDI + scn);
        if (t < 128) rbc = *(const float4*)(bc_base + (size_t)(l0 + rb) * kNX + cbo);
    };
    auto store_chunk = [&]() {
        *(float4*)&uS [sr][scn] = ru;
        *(float4*)&gS [sr][scn] = rg;
        *(float4*)&dtS[sr][scn] = rdt;
        if (t < 128) *(float4*)&bcS[rb][cbo] = rbc;
    };

    f32x4 h   = {0.f, 0.f, 0.f, 0.f};
    f32x4 cp  = {1.f, 1.f, 1.f, 1.f};
    f32x4 acc = {0.f, 0.f, 0.f, 0.f};
    f32x4 wc  = {0.f, 0.f, 0.f, 0.f};
    float ug = 0.f;

    load_chunk(lb);
    store_chunk();
    __syncthreads();

    #pragma unroll
    for (int ck = 0; ck < kSEGL / kCT; ++ck) {
        if (ck + 1 < kSEGL / kCT) load_chunk(lb + (ck + 1) * kCT);
        #pragma unroll 8
        for (int i = 0; i < kCT; ++i) {
            const float dtv = dtS[i][c];
            const float uv  = uS [i][c];
            const float gv  = gS [i][c];
            const f32x4 Bv = *(const f32x4*)&bcS[i][sq * 4];        // uniform
            const f32x4 Cv = *(const f32x4*)&bcS[i][16 + sq * 4];   // uniform
            const f32x4 pm = dtv * Av;
            f32x4 dA;
            dA.x = exp2f(pm.x); dA.y = exp2f(pm.y);
            dA.z = exp2f(pm.z); dA.w = exp2f(pm.w);
            const float dtu = dtv * uv;
            h  = dA * h + dtu * Bv;
            cp = cp * dA;
            const f32x4 cg = Cv * gv;
            acc = h * cg + acc;
            wc  = cp * cg + wc;
            ug  = fmaf(uv, gv, ug);
        }
        if (ck + 1 < kSEGL / kCT) {
            __syncthreads();
            store_chunk();
            __syncthreads();
        }
    }

    // coalesced: [seg][sq][b*kDI+d][4] — lane stride 16B
    const size_t o = (size_t)seg * kP + ((size_t)sq * kBD + b * kDI + d) * 4;
    *(f32x4*)&PA[o]   = cp;
    *(f32x4*)&QA[o]   = h;
    *(f32x4*)&accA[o] = acc;
    *(f32x4*)&wcA[o]  = wc;
    if (sq == 0) ugA[(size_t)seg * kBD + b * kDI + d] = ug;
}

// Pass 2: chain segments (transposed layout), reduce states, add D*ug.
__global__ __launch_bounds__(256) void scan_combine_kernel(
    const float* __restrict__ PA, const float* __restrict__ QA,
    const float* __restrict__ accA, const float* __restrict__ wcA,
    const float* __restrict__ ugA, const float* __restrict__ Dvec,
    float* __restrict__ ysum)
{
    const int p = blockIdx.x * 256 + threadIdx.x;   // 0..kP-1
    const int s = p & 15;
    const int bd = p >> 4;                          // b*kDI + d
    const size_t pbase = ((size_t)(s >> 2) * kBD + bd) * 4 + (s & 3);
    float h = 0.f, tot = 0.f;
    #pragma unroll
    for (int seg = 0; seg < kNSEG; ++seg) {
        const size_t o = (size_t)seg * kP + pbase;
        tot += accA[o] + h * wcA[o];
        h = fmaf(PA[o], h, QA[o]);
    }
    #pragma unroll
    for (int o2 = 1; o2 < 16; o2 <<= 1) tot += __shfl_xor(tot, o2, 64);
    if (s == 0) {
        float ug = 0.f;
        #pragma unroll
        for (int seg = 0; seg < kNSEG; ++seg)
            ug += ugA[(size_t)seg * kBD + bd];
        ysum[bd] = tot + Dvec[bd % kDI] * ug;
    }
}

// ---------------------------------------------------------------------------
// out[b][j] = (1/L) * sum_d ysum[b][d] * Wout[j][d]
__global__ __launch_bounds__(256) void final_kernel(
    const float* __restrict__ ysum, const float* __restrict__ Wout,
    float* __restrict__ out)
{
    int gw = blockIdx.x * 4 + (threadIdx.x >> 6);
    int lane = threadIdx.x & 63;
    int b = gw / kDM;
    int j = gw - b * kDM;
    const float* yrow = ysum + (size_t)b * kDI;
    const float* wrow = Wout + (size_t)j * kDI;
    float acc = 0.f;
    for (int k = lane; k < kDI; k += 64) acc = fmaf(yrow[k], wrow[k], acc);
    #pragma unroll
    for (int o = 32; o; o >>= 1) acc += __shfl_xor(acc, o, 64);
    if (lane == 0) out[gw] = acc * (1.f / (float)kL);
}

// ---------------------------------------------------------------------------
extern "C" void kernel_launch(void* const* d_in, const int* in_sizes, int n_in,
                              void* d_out, int out_size, void* d_ws, size_t ws_size,
                              hipStream_t stream)
{
    const float* image_tokens = (const float*)d_in[0];
    const float* text_tokens  = (const float*)d_in[1];
    const float* W_txt        = (const float*)d_in[2];
    const float* b_txt        = (const float*)d_in[3];
    const float* in_proj_w    = (const float*)d_in[4];
    const float* conv_w       = (const float*)d_in[5];
    const float* conv_b       = (const float*)d_in[6];
    const float* x_proj_w     = (const float*)d_in[7];
    const float* dt_proj_w    = (const float*)d_in[8];
    const float* dt_proj_b    = (const float*)d_in[9];
    const float* A_log        = (const float*)d_in[10];
    const float* Dvec         = (const float*)d_in[11];
    const float* out_proj_w   = (const float*)d_in[12];
    float* out = (float*)d_out;

    // workspace layout (bytes, all 256B-aligned). Region lifetimes:
    //   dtreg: tokb+wb (until in_proj) -> part (xproj) -> dt (dtproj..scan)
    //   xraw:  conv input (until conv) -> PA/QA/accA/wcA partials (scan..combine)
    char* p = (char*)d_ws;
    float* txt  = (float*)p;                      p += 12288;
    float* dtreg = (float*)p;                     p += (size_t)kM * kDI * 4;       // 25.2 MB
    float* xraw = (float*)p;                      p += (size_t)kM * kDI * 4;       // 25.2 MB
    float* gbuf = (float*)p;                      p += (size_t)kM * kDI * 4;       // 25.2 MB
    float* xbuf = (float*)p;                      p += (size_t)kM * kDI * 4;       // 25.2 MB
    float* xdbl = (float*)p;                      p += (size_t)kM * kNX * 4;       // 1.3 MB
    float* ysum = (float*)p;                      p += 32768;
    float* ugA  = (float*)p;                      p += (size_t)kNSEG * kBD * 4;    // 0.4 MB

    unsigned short* tokb = (unsigned short*)dtreg;          // 6.3 MB
    unsigned short* wb   = tokb + (size_t)kM * kDM;         // 4.7 MB
    float* part = dtreg;                                    // 10.5 MB (after in_proj)
    float* dtb  = dtreg;                                    // 25.2 MB (after xproj)
    float* PA   = xraw;                                     // partials
    float* QA   = PA + (size_t)kNSEG * kP;
    float* accA = QA + (size_t)kNSEG * kP;
    float* wcA  = accA + (size_t)kNSEG * kP;

    // 1) txt projection
    txt_kernel<<<dim3(kB * kDM / 4), dim3(256), 0, stream>>>(text_tokens, W_txt, b_txt, txt);

    // 2) tokens = bf16(image + txt)
    tokens_bf16_kernel<<<dim3(kM * kDM / 4 / 256), dim3(256), 0, stream>>>(image_tokens, txt, tokb);

    // 3) cast in_proj_w to bf16
    castw_kernel<<<dim3((2 * kDI * kDM / 4 + 255) / 256), dim3(256), 0, stream>>>(
        in_proj_w, wb, 2 * kDI * kDM / 4);

    // 4) in_proj (bf16 MFMA): x half -> xraw, z half -> g = silu(z)
    mfma_inproj_kernel<<<dim3(kM / 128, 2 * kDI / 128), dim3(256), 0, stream>>>(
        tokb, wb, xraw, gbuf);

    // 5) causal conv + silu (float4)
    conv_silu_kernel<<<dim3(kM * kDI / 4 / 256), dim3(256), 0, stream>>>(
        xraw, conv_w, conv_b, xbuf);

    // 6) x_proj split-K (part overlays dtreg; tokb/wb dead now)
    xproj_splitk_kernel<<<dim3(kM / 64, kKS), dim3(256), 0, stream>>>(xbuf, x_proj_w, part);
    xproj_reduce_kernel<<<dim3(kM * kNX / 256), dim3(256), 0, stream>>>(part, xdbl);

    // 7) dt_proj (round-2 proven gemm structure) -> dtb
    dtproj_gemm_kernel<<<dim3(kM / 64, kDI / 64), dim3(256), 0, stream>>>(
        xdbl, dt_proj_w, dt_proj_b, dtb);

    // 8) full-residency segmented scan + combine
    scan10_kernel<<<dim3(kB * 24 * kNSEG), dim3(256), 0, stream>>>(
        xbuf, gbuf, dtb, xdbl, A_log, PA, QA, accA, wcA, ugA);
    scan_combine_kernel<<<dim3(kP / 256), dim3(256), 0, stream>>>(
        PA, QA, accA, wcA, ugA, Dvec, ysum);

    // 9) out = (ysum/L) @ out_proj_w.T
    final_kernel<<<dim3(kB * kDM / 4), dim3(256), 0, stream>>>(ysum, out_proj_w, out);
}

// Round 14
// 185.465 us; speedup vs baseline: 1.6266x; 1.0153x over previous
//
#include <hip/hip_runtime.h>
#include <math.h>

// Problem constants
constexpr int kB   = 4;
constexpr int kL   = 1024;
constexpr int kDM  = 768;
constexpr int kDI  = 1536;   // 2*kDM
constexpr int kDS  = 16;     // D_STATE
constexpr int kDTR = 48;     // DT_RANK
constexpr int kNX  = 80;     // DTR + 2*DS
constexpr int kM   = kB * kL; // 4096
constexpr int kLTXT = 128;

typedef __attribute__((ext_vector_type(8))) short bf16x8;
typedef __attribute__((ext_vector_type(4))) float f32x4;
typedef __attribute__((ext_vector_type(8))) unsigned short u16x8;

__device__ inline unsigned short f2bf(float f) {
    unsigned u = __float_as_uint(f);
    u = (u + 0x7FFFu + ((u >> 16) & 1u)) >> 16;   // RNE
    return (unsigned short)u;
}
__device__ inline float bf2f(unsigned short us) {
    return __uint_as_float((unsigned)us << 16);
}

__device__ __forceinline__ void gl2lds16(const unsigned short* g, unsigned short* l) {
    __builtin_amdgcn_global_load_lds(
        (const __attribute__((address_space(1))) unsigned int*)g,
        (__attribute__((address_space(3))) unsigned int*)l, 16, 0, 0);
}

// ---------------------------------------------------------------------------
// txt[b][j] = b_txt[j] + sum_k text_tokens[b,0,k] * W_txt[j,k]
__global__ __launch_bounds__(256) void txt_kernel(
    const float* __restrict__ text, const float* __restrict__ Wt,
    const float* __restrict__ bt, float* __restrict__ txt)
{
    int gw = blockIdx.x * 4 + (threadIdx.x >> 6);
    int lane = threadIdx.x & 63;
    int b = gw / kDM;
    int j = gw - b * kDM;
    const float* trow = text + (size_t)b * kLTXT * kDM;
    const float* wrow = Wt + (size_t)j * kDM;
    float acc = 0.f;
    for (int k = lane; k < kDM; k += 64) acc = fmaf(trow[k], wrow[k], acc);
    #pragma unroll
    for (int o = 32; o; o >>= 1) acc += __shfl_xor(acc, o, 64);
    if (lane == 0) txt[gw] = acc + bt[j];
}

// ---------------------------------------------------------------------------
// Merged prep: blocks [0,3072): tokens_bf16 = bf16(image + txt)
//              blocks [3072,5376): cast in_proj_w -> bf16
__global__ __launch_bounds__(256) void prep_kernel(
    const float* __restrict__ img, const float* __restrict__ txt,
    unsigned short* __restrict__ tok,
    const float* __restrict__ w, unsigned short* __restrict__ wb)
{
    const int bid = blockIdx.x;
    if (bid < 3072) {
        int i = bid * 256 + threadIdx.x;           // over kM*kDM/4
        float4 a = ((const float4*)img)[i];
        int m = i / (kDM / 4);
        int k4 = i - m * (kDM / 4);
        float4 tv = ((const float4*)(txt + (size_t)(m >> 10) * kDM))[k4];
        ushort4 o;
        o.x = f2bf(a.x + tv.x); o.y = f2bf(a.y + tv.y);
        o.z = f2bf(a.z + tv.z); o.w = f2bf(a.w + tv.w);
        ((ushort4*)tok)[i] = o;
    } else {
        int i = (bid - 3072) * 256 + threadIdx.x;  // over 2*kDI*kDM/4
        float4 a = ((const float4*)w)[i];
        ushort4 v;
        v.x = f2bf(a.x); v.y = f2bf(a.y); v.z = f2bf(a.z); v.w = f2bf(a.w);
        ((ushort4*)wb)[i] = v;
    }
}

// ---------------------------------------------------------------------------
// bf16 MFMA GEMM for in_proj (global_load_lds width-16, double-buffered LDS).
// M=4096, N=3072, K=768. BM=BN=128, BK=32, 256 threads (4 waves, 2x2).
// n<1536 -> xout (f32); n>=1536 -> gout = bf16(silu(v))
__global__ __launch_bounds__(256) void mfma_inproj_kernel(
    const unsigned short* __restrict__ A, const unsigned short* __restrict__ W,
    float* __restrict__ xout, unsigned short* __restrict__ gout)
{
    __shared__ unsigned short Asm[2][128][32];
    __shared__ unsigned short Wsm[2][128][32];
    const int t = threadIdx.x;
    const int lane = t & 63;
    const int wv = t >> 6;             // wave 0..3
    const int wr = wv >> 1, wc = wv & 1;
    const int m0 = blockIdx.x * 128;
    const int n0 = blockIdx.y * 128;

    const int srow = lane >> 2;          // 0..15
    const int scol = (lane & 3) * 8;     // bf16 elem 0,8,16,24
    const unsigned short* agp  = A + (size_t)(m0 + wv * 32 + srow) * kDM + scol;
    const unsigned short* agp2 = agp + 16 * kDM;
    const unsigned short* wgp  = W + (size_t)(n0 + wv * 32 + srow) * kDM + scol;
    const unsigned short* wgp2 = wgp + 16 * kDM;

    auto stage = [&](int buf, int k0) {
        gl2lds16(agp  + k0, &Asm[buf][wv * 32][0]);
        gl2lds16(agp2 + k0, &Asm[buf][wv * 32 + 16][0]);
        gl2lds16(wgp  + k0, &Wsm[buf][wv * 32][0]);
        gl2lds16(wgp2 + k0, &Wsm[buf][wv * 32 + 16][0]);
    };

    f32x4 acc[4][4] = {};
    const int fr = lane & 15;
    const int fk = (lane >> 4) * 8;

    stage(0, 0);
    __syncthreads();

    int buf = 0;
    for (int k0 = 0; k0 < kDM; k0 += 32) {
        if (k0 + 32 < kDM) stage(buf ^ 1, k0 + 32);
        bf16x8 af[4], wf[4];
        #pragma unroll
        for (int i = 0; i < 4; ++i)
            af[i] = *(const bf16x8*)&Asm[buf][wr * 64 + i * 16 + fr][fk];
        #pragma unroll
        for (int j = 0; j < 4; ++j)
            wf[j] = *(const bf16x8*)&Wsm[buf][wc * 64 + j * 16 + fr][fk];
        #pragma unroll
        for (int i = 0; i < 4; ++i)
            #pragma unroll
            for (int j = 0; j < 4; ++j)
                acc[i][j] = __builtin_amdgcn_mfma_f32_16x16x32_bf16(af[i], wf[j], acc[i][j], 0, 0, 0);
        __syncthreads();
        buf ^= 1;
    }

    const int erow = (lane >> 4) * 4;
    const int ecol = lane & 15;
    #pragma unroll
    for (int i = 0; i < 4; ++i) {
        #pragma unroll
        for (int j = 0; j < 4; ++j) {
            const int gn = n0 + wc * 64 + j * 16 + ecol;
            #pragma unroll
            for (int q = 0; q < 4; ++q) {
                const int gm = m0 + wr * 64 + i * 16 + erow + q;
                float v = acc[i][j][q];
                if (gn < kDI) {
                    xout[(size_t)gm * kDI + gn] = v;
                } else {
                    gout[(size_t)gm * kDI + (gn - kDI)] = f2bf(v / (1.f + __expf(-v)));
                }
            }
        }
    }
}

// ---------------------------------------------------------------------------
// x_proj split-K: part[ks][m][n] = sum_{k in seg ks} x[m][k] * W[n][k]
constexpr int kKS   = 8;
constexpr int kKSEG = kDI / kKS;   // 192

__global__ __launch_bounds__(256) void xproj_splitk_kernel(
    const float* __restrict__ A, const float* __restrict__ W,
    float* __restrict__ part)
{
    __shared__ float As[16][68];
    __shared__ float Ws[16][84];
    const int t = threadIdx.x;
    const int m0 = blockIdx.x * 64;
    const int kbase = blockIdx.y * kKSEG;
    const int lrow = t >> 2, lk4 = (t & 3) << 2;
    const int ci = (t & 15) << 2;      // 4 rows
    const int cj = (t >> 4) * 5;       // 5 cols (16*5 = 80)
    float acc[4][5] = {};
    const float* aptr = A + (size_t)(m0 + lrow) * kDI + kbase + lk4;

    for (int k0 = 0; k0 < kKSEG; k0 += 16) {
        float4 av = *(const float4*)(aptr + k0);
        if (k0) __syncthreads();
        As[lk4+0][lrow] = av.x; As[lk4+1][lrow] = av.y;
        As[lk4+2][lrow] = av.z; As[lk4+3][lrow] = av.w;
        #pragma unroll
        for (int i = 0; i < 5; ++i) {
            int idx = t + 256 * i;
            int n = idx % 80;
            int k = idx / 80;
            Ws[k][n] = W[(size_t)n * kDI + kbase + k0 + k];
        }
        __syncthreads();
        #pragma unroll
        for (int k = 0; k < 16; ++k) {
            const float4 a4 = *(const float4*)&As[k][ci];
            const float aa[4] = {a4.x, a4.y, a4.z, a4.w};
            float ww[5];
            #pragma unroll
            for (int j = 0; j < 5; ++j) ww[j] = Ws[k][cj + j];
            #pragma unroll
            for (int i = 0; i < 4; ++i)
                #pragma unroll
                for (int j = 0; j < 5; ++j)
                    acc[i][j] = fmaf(aa[i], ww[j], acc[i][j]);
        }
    }

    float* pbase = part + ((size_t)blockIdx.y * kM) * kNX;
    #pragma unroll
    for (int i = 0; i < 4; ++i)
        #pragma unroll
        for (int j = 0; j < 5; ++j)
            pbase[(size_t)(m0 + ci + i) * kNX + cj + j] = acc[i][j];
}

__global__ __launch_bounds__(256) void xproj_reduce_kernel(
    const float* __restrict__ part, float* __restrict__ xdbl)
{
    int i = blockIdx.x * 256 + threadIdx.x;    // over kM*kNX
    float s = 0.f;
    #pragma unroll
    for (int k = 0; k < kKS; ++k) s += part[(size_t)k * kM * kNX + i];
    xdbl[i] = s;
}

// ---------------------------------------------------------------------------
// dt_proj (proven round-2 gemm structure, VGPR ~36) -> bf16 output.
// dt[m][n] = softplus(sum_k xdbl[m][k]*Wd[n][k] + b[n]); K=48, BK=16.
__global__ __launch_bounds__(256) void dtproj_gemm_kernel(
    const float* __restrict__ A, const float* __restrict__ W,
    const float* __restrict__ bias, unsigned short* __restrict__ dt)
{
    __shared__ float As[16][68];
    __shared__ float Ws[16][68];
    const int t = threadIdx.x;
    const int m0 = blockIdx.x * 64;
    const int n0 = blockIdx.y * 64;
    const int lrow = t >> 2;          // 0..63
    const int lk4  = (t & 3) << 2;    // 0,4,8,12
    const int ci   = (t & 15) << 2;
    const int cj   = (t >> 4) << 2;
    float acc[4][4] = {};
    const float* aptr = A + (size_t)(m0 + lrow) * kNX + lk4;
    const float* wptr = W + (size_t)(n0 + lrow) * kDTR + lk4;

    for (int k0 = 0; k0 < kDTR; k0 += 16) {
        float4 av = *(const float4*)(aptr + k0);
        float4 wv = *(const float4*)(wptr + k0);
        if (k0) __syncthreads();
        As[lk4+0][lrow] = av.x; As[lk4+1][lrow] = av.y;
        As[lk4+2][lrow] = av.z; As[lk4+3][lrow] = av.w;
        Ws[lk4+0][lrow] = wv.x; Ws[lk4+1][lrow] = wv.y;
        Ws[lk4+2][lrow] = wv.z; Ws[lk4+3][lrow] = wv.w;
        __syncthreads();
        #pragma unroll
        for (int k = 0; k < 16; ++k) {
            const float4 a4 = *(const float4*)&As[k][ci];
            const float4 w4 = *(const float4*)&Ws[k][cj];
            const float aa[4] = {a4.x, a4.y, a4.z, a4.w};
            const float ww[4] = {w4.x, w4.y, w4.z, w4.w};
            #pragma unroll
            for (int i = 0; i < 4; ++i)
                #pragma unroll
                for (int j = 0; j < 4; ++j)
                    acc[i][j] = fmaf(aa[i], ww[j], acc[i][j]);
        }
    }

    #pragma unroll
    for (int i = 0; i < 4; ++i) {
        const int gm = m0 + ci + i;
        ushort4 o;
        unsigned short* op = (unsigned short*)&o;
        #pragma unroll
        for (int j = 0; j < 4; ++j) {
            float v = acc[i][j] + bias[n0 + cj + j];
            v = (v > 20.f) ? v : log1pf(__expf(v));   // softplus
            op[j] = f2bf(v);
        }
        *(ushort4*)&dt[(size_t)gm * kDI + n0 + cj] = o;
    }
}

// ---------------------------------------------------------------------------
// causal depthwise conv (k=4) + SiLU, float4 over d
__global__ __launch_bounds__(256) void conv_silu_kernel(
    const float* __restrict__ xraw, const float* __restrict__ cw,
    const float* __restrict__ cb, float* __restrict__ xout)
{
    int i = blockIdx.x * 256 + threadIdx.x;     // over kM*kDI/4
    int d4 = i % (kDI / 4);
    int ml = i / (kDI / 4);
    int l = ml & (kL - 1);
    const int d = d4 * 4;
    float4 acc = *(const float4*)&cb[d];
    const float* base = xraw + (size_t)ml * kDI + d - 3 * (size_t)kDI;
    float4 w0 = *(const float4*)&cw[(d + 0) * 4];
    float4 w1 = *(const float4*)&cw[(d + 1) * 4];
    float4 w2 = *(const float4*)&cw[(d + 2) * 4];
    float4 w3 = *(const float4*)&cw[(d + 3) * 4];
    const float wj[4][4] = {{w0.x, w1.x, w2.x, w3.x}, {w0.y, w1.y, w2.y, w3.y},
                            {w0.z, w1.z, w2.z, w3.z}, {w0.w, w1.w, w2.w, w3.w}};
    #pragma unroll
    for (int j = 0; j < 4; ++j) {
        if (l - 3 + j >= 0) {
            float4 xv = *(const float4*)(base + (size_t)j * kDI);
            acc.x = fmaf(xv.x, wj[j][0], acc.x);
            acc.y = fmaf(xv.y, wj[j][1], acc.y);
            acc.z = fmaf(xv.z, wj[j][2], acc.z);
            acc.w = fmaf(xv.w, wj[j][3], acc.w);
        }
    }
    acc.x /= (1.f + __expf(-acc.x));
    acc.y /= (1.f + __expf(-acc.y));
    acc.z /= (1.f + __expf(-acc.z));
    acc.w /= (1.f + __expf(-acc.w));
    *(float4*)&xout[(size_t)ml * kDI + d] = acc;
}

// ---------------------------------------------------------------------------
// Selective scan v11: scan10 with bf16 g/dt inputs (converted to f32 at
// staging time — inner loop unchanged). LDS 14.1 KB.
constexpr int kNSEG = 16;
constexpr int kSEGL = kL / kNSEG;     // 64
constexpr int kCT   = 16;             // steps per chunk
constexpr int kBD   = kB * kDI;       // 6144
constexpr int kP    = kBD * 16;       // 98304 (b,d,s) tuples
constexpr float kLOG2E = 1.44269504089f;

__global__ __launch_bounds__(256, 6) void scan11_kernel(
    const float* __restrict__ u, const unsigned short* __restrict__ g,
    const unsigned short* __restrict__ dt, const float* __restrict__ xdbl,
    const float* __restrict__ A_log,
    float* __restrict__ PA, float* __restrict__ QA,
    float* __restrict__ accA, float* __restrict__ wcA,
    float* __restrict__ ugA)
{
    __shared__ float uS [kCT][64];     // 4 KB
    __shared__ float gS [kCT][64];     // 4 KB
    __shared__ float dtS[kCT][64];     // 4 KB
    __shared__ float bcS[kCT][34];     // B|C (32 used) + pad   2.1 KB
    const int t = threadIdx.x;
    const int blk = blockIdx.x;          // grid = 96 * kNSEG = 1536
    const int seg = blk & (kNSEG - 1);
    const int bd  = blk >> 4;            // 0..95
    const int b   = bd / 24;
    const int d0  = (bd % 24) * 64;
    const int c   = t & 63;              // channel
    const int sq  = t >> 6;              // state-quad (wave-uniform)
    const int d   = d0 + c;
    const int lb  = seg * kSEGL;

    f32x4 Av;
    {
        float4 al = *(const float4*)&A_log[d * kDS + sq * 4];
        Av.x = -__expf(al.x) * kLOG2E;
        Av.y = -__expf(al.y) * kLOG2E;
        Av.z = -__expf(al.z) * kLOG2E;
        Av.w = -__expf(al.w) * kLOG2E;
    }

    const float* u_base           = u  + ((size_t)b << 10) * kDI + d0;
    const unsigned short* g_base  = g  + ((size_t)b << 10) * kDI + d0;
    const unsigned short* dt_base = dt + ((size_t)b << 10) * kDI + d0;
    const float* bc_base = xdbl + ((size_t)b << 10) * kNX + kDTR;
    const int sr = t >> 4, scn = (t & 15) * 4;   // u: [16][64], 1 f4/thread
    const int hr = (t & 127) >> 3, hc = ((t & 127) & 7) * 8;  // g/dt: u16x8
    const int rb = (t & 127) >> 3, cbo = ((t & 127) & 7) * 4; // bc: [16][32]

    float4 ru, rbc;
    u16x8 rgd;
    auto load_chunk = [&](int l0) {
        ru = *(const float4*)(u_base + (size_t)(l0 + sr) * kDI + scn);
        if (t < 128) {
            rgd = *(const u16x8*)(g_base + (size_t)(l0 + hr) * kDI + hc);
            rbc = *(const float4*)(bc_base + (size_t)(l0 + rb) * kNX + cbo);
        } else {
            rgd = *(const u16x8*)(dt_base + (size_t)(l0 + hr) * kDI + hc);
        }
    };
    auto store_chunk = [&]() {
        *(float4*)&uS[sr][scn] = ru;
        float* dst = (t < 128) ? &gS[hr][hc] : &dtS[hr][hc];
        float4 lo, hi;
        lo.x = bf2f(rgd[0]); lo.y = bf2f(rgd[1]);
        lo.z = bf2f(rgd[2]); lo.w = bf2f(rgd[3]);
        hi.x = bf2f(rgd[4]); hi.y = bf2f(rgd[5]);
        hi.z = bf2f(rgd[6]); hi.w = bf2f(rgd[7]);
        *(float4*)(dst)     = lo;
        *(float4*)(dst + 4) = hi;
        if (t < 128) *(float4*)&bcS[rb][cbo] = rbc;
    };

    f32x4 h   = {0.f, 0.f, 0.f, 0.f};
    f32x4 cp  = {1.f, 1.f, 1.f, 1.f};
    f32x4 acc = {0.f, 0.f, 0.f, 0.f};
    f32x4 wc  = {0.f, 0.f, 0.f, 0.f};
    float ug = 0.f;

    load_chunk(lb);
    store_chunk();
    __syncthreads();

    #pragma unroll
    for (int ck = 0; ck < kSEGL / kCT; ++ck) {
        if (ck + 1 < kSEGL / kCT) load_chunk(lb + (ck + 1) * kCT);
        #pragma unroll 8
        for (int i = 0; i < kCT; ++i) {
            const float dtv = dtS[i][c];
            const float uv  = uS [i][c];
            const float gv  = gS [i][c];
            const f32x4 Bv = *(const f32x4*)&bcS[i][sq * 4];        // uniform
            const f32x4 Cv = *(const f32x4*)&bcS[i][16 + sq * 4];   // uniform
            const f32x4 pm = dtv * Av;
            f32x4 dA;
            dA.x = exp2f(pm.x); dA.y = exp2f(pm.y);
            dA.z = exp2f(pm.z); dA.w = exp2f(pm.w);
            const float dtu = dtv * uv;
            h  = dA * h + dtu * Bv;
            cp = cp * dA;
            const f32x4 cg = Cv * gv;
            acc = h * cg + acc;
            wc  = cp * cg + wc;
            ug  = fmaf(uv, gv, ug);
        }
        if (ck + 1 < kSEGL / kCT) {
            __syncthreads();
            store_chunk();
            __syncthreads();
        }
    }

    // coalesced: [seg][sq][b*kDI+d][4] — lane stride 16B
    const size_t o = (size_t)seg * kP + ((size_t)sq * kBD + b * kDI + d) * 4;
    *(f32x4*)&PA[o]   = cp;
    *(f32x4*)&QA[o]   = h;
    *(f32x4*)&accA[o] = acc;
    *(f32x4*)&wcA[o]  = wc;
    if (sq == 0) ugA[(size_t)seg * kBD + b * kDI + d] = ug;
}

// Pass 2: chain segments (transposed layout), reduce states, add D*ug.
__global__ __launch_bounds__(256) void scan_combine_kernel(
    const float* __restrict__ PA, const float* __restrict__ QA,
    const float* __restrict__ accA, const float* __restrict__ wcA,
    const float* __restrict__ ugA, const float* __restrict__ Dvec,
    float* __restrict__ ysum)
{
    const int p = blockIdx.x * 256 + threadIdx.x;   // 0..kP-1
    const int s = p & 15;
    const int bd = p >> 4;                          // b*kDI + d
    const size_t pbase = ((size_t)(s >> 2) * kBD + bd) * 4 + (s & 3);
    float h = 0.f, tot = 0.f;
    #pragma unroll
    for (int seg = 0; seg < kNSEG; ++seg) {
        const size_t o = (size_t)seg * kP + pbase;
        tot += accA[o] + h * wcA[o];
        h = fmaf(PA[o], h, QA[o]);
    }
    #pragma unroll
    for (int o2 = 1; o2 < 16; o2 <<= 1) tot += __shfl_xor(tot, o2, 64);
    if (s == 0) {
        float ug = 0.f;
        #pragma unroll
        for (int seg = 0; seg < kNSEG; ++seg)
            ug += ugA[(size_t)seg * kBD + bd];
        ysum[bd] = tot + Dvec[bd % kDI] * ug;
    }
}

// ---------------------------------------------------------------------------
// out[b][j] = (1/L) * sum_d ysum[b][d] * Wout[j][d]
__global__ __launch_bounds__(256) void final_kernel(
    const float* __restrict__ ysum, const float* __restrict__ Wout,
    float* __restrict__ out)
{
    int gw = blockIdx.x * 4 + (threadIdx.x >> 6);
    int lane = threadIdx.x & 63;
    int b = gw / kDM;
    int j = gw - b * kDM;
    const float* yrow = ysum + (size_t)b * kDI;
    const float* wrow = Wout + (size_t)j * kDI;
    float acc = 0.f;
    for (int k = lane; k < kDI; k += 64) acc = fmaf(yrow[k], wrow[k], acc);
    #pragma unroll
    for (int o = 32; o; o >>= 1) acc += __shfl_xor(acc, o, 64);
    if (lane == 0) out[gw] = acc * (1.f / (float)kL);
}

// ---------------------------------------------------------------------------
extern "C" void kernel_launch(void* const* d_in, const int* in_sizes, int n_in,
                              void* d_out, int out_size, void* d_ws, size_t ws_size,
                              hipStream_t stream)
{
    const float* image_tokens = (const float*)d_in[0];
    const float* text_tokens  = (const float*)d_in[1];
    const float* W_txt        = (const float*)d_in[2];
    const float* b_txt        = (const float*)d_in[3];
    const float* in_proj_w    = (const float*)d_in[4];
    const float* conv_w       = (const float*)d_in[5];
    const float* conv_b       = (const float*)d_in[6];
    const float* x_proj_w     = (const float*)d_in[7];
    const float* dt_proj_w    = (const float*)d_in[8];
    const float* dt_proj_b    = (const float*)d_in[9];
    const float* A_log        = (const float*)d_in[10];
    const float* Dvec         = (const float*)d_in[11];
    const float* out_proj_w   = (const float*)d_in[12];
    float* out = (float*)d_out;

    // workspace layout (bytes, all 256B-aligned). Region lifetimes:
    //   dtreg: tokb+wb (until in_proj) -> part (xproj) -> dt bf16 (dtproj..scan)
    //   xraw:  conv input (until conv) -> PA/QA/accA/wcA partials (scan..combine)
    //   gbuf:  bf16 g (in_proj..scan), uses half its 25.2MB region
    char* p = (char*)d_ws;
    float* txt  = (float*)p;                      p += 12288;
    float* dtreg = (float*)p;                     p += (size_t)kM * kDI * 4;       // 25.2 MB
    float* xraw = (float*)p;                      p += (size_t)kM * kDI * 4;       // 25.2 MB
    unsigned short* gbuf = (unsigned short*)p;    p += (size_t)kM * kDI * 4;       // 25.2 MB region (12.6 used)
    float* xbuf = (float*)p;                      p += (size_t)kM * kDI * 4;       // 25.2 MB
    float* xdbl = (float*)p;                      p += (size_t)kM * kNX * 4;       // 1.3 MB
    float* ysum = (float*)p;                      p += 32768;
    float* ugA  = (float*)p;                      p += (size_t)kNSEG * kBD * 4;    // 0.4 MB

    unsigned short* tokb = (unsigned short*)dtreg;          // 6.3 MB
    unsigned short* wb   = tokb + (size_t)kM * kDM;         // 4.7 MB
    float* part = dtreg;                                    // 10.5 MB (after in_proj)
    unsigned short* dtb = (unsigned short*)dtreg;           // 12.6 MB (after xproj)
    float* PA   = xraw;                                     // partials
    float* QA   = PA + (size_t)kNSEG * kP;
    float* accA = QA + (size_t)kNSEG * kP;
    float* wcA  = accA + (size_t)kNSEG * kP;

    // 1) txt projection
    txt_kernel<<<dim3(kB * kDM / 4), dim3(256), 0, stream>>>(text_tokens, W_txt, b_txt, txt);

    // 2) merged prep: tokens = bf16(image + txt)  +  cast in_proj_w -> bf16
    prep_kernel<<<dim3(3072 + 2304), dim3(256), 0, stream>>>(
        image_tokens, txt, tokb, in_proj_w, wb);

    // 3) in_proj (bf16 MFMA): x half -> xraw (f32), z half -> g = bf16(silu(z))
    mfma_inproj_kernel<<<dim3(kM / 128, 2 * kDI / 128), dim3(256), 0, stream>>>(
        tokb, wb, xraw, gbuf);

    // 4) causal conv + silu (float4)
    conv_silu_kernel<<<dim3(kM * kDI / 4 / 256), dim3(256), 0, stream>>>(
        xraw, conv_w, conv_b, xbuf);

    // 5) x_proj split-K (part overlays dtreg; tokb/wb dead now)
    xproj_splitk_kernel<<<dim3(kM / 64, kKS), dim3(256), 0, stream>>>(xbuf, x_proj_w, part);
    xproj_reduce_kernel<<<dim3(kM * kNX / 256), dim3(256), 0, stream>>>(part, xdbl);

    // 6) dt_proj -> bf16 dtb (overlays dtreg; part dead now)
    dtproj_gemm_kernel<<<dim3(kM / 64, kDI / 64), dim3(256), 0, stream>>>(
        xdbl, dt_proj_w, dt_proj_b, dtb);

    // 7) full-residency segmented scan (bf16 g/dt) + combine
    scan11_kernel<<<dim3(kB * 24 * kNSEG), dim3(256), 0, stream>>>(
        xbuf, gbuf, dtb, xdbl, A_log, PA, QA, accA, wcA, ugA);
    scan_combine_kernel<<<dim3(kP / 256), dim3(256), 0, stream>>>(
        PA, QA, accA, wcA, ugA, Dvec, ysum);

    // 8) out = (ysum/L) @ out_proj_w.T
    final_kernel<<<dim3(kB * kDM / 4), dim3(256), 0, stream>>>(ysum, out_proj_w, out);
}